// Round 9
// baseline (307.756 us; speedup 1.0000x reference)
//
#include <hip/hip_runtime.h>
#include <math.h>

// Problem constants
constexpr int Bsz  = 8;
constexpr int Ntok = 1920;
constexpr int Cdim = 512;
constexpr int BLK  = 192;
constexpr int Mrows = Bsz * Ntok;      // 15360
constexpr int NBLK  = Mrows / BLK;     // 80
constexpr float SCALE = 0.02209708691207961f;  // 2048^-0.5

typedef _Float16 half8 __attribute__((ext_vector_type(8)));
typedef float    f32x4 __attribute__((ext_vector_type(4)));

#define GLOAD_LDS16(gp, lp) __builtin_amdgcn_global_load_lds( \
    (const __attribute__((address_space(1))) void*)(gp),      \
    (__attribute__((address_space(3))) void*)(lp), 16, 0, 0)

// chunk swizzle within a 64B row (4 x 16B chunks): applied on BOTH the global
// source chunk (staging) and the ds_read chunk -> involution, banks spread.
__device__ inline int sfun(int r) { return (r & 3) ^ ((r >> 2) & 3); }

// ---- f16 helpers ----
__device__ inline unsigned short f2h(float f) {
    _Float16 h = (_Float16)f;
    return __builtin_bit_cast(unsigned short, h);
}
__device__ inline float h2f(unsigned short u) {
    return (float)__builtin_bit_cast(_Float16, u);
}

// ---------------- token mean (two-stage) ----------------
__global__ void mean_partial(const float* __restrict__ g, float* __restrict__ part) {
    int b = blockIdx.x, t = blockIdx.y, c = threadIdx.x;
    const float* p = g + ((size_t)b * Ntok + (size_t)t * 48) * Cdim + c;
    float s = 0.f;
    #pragma unroll 4
    for (int n = 0; n < 48; ++n) s += p[(size_t)n * Cdim];
    part[((size_t)b * 40 + t) * Cdim + c] = s;
}

__global__ void mean_final(const float* __restrict__ part, float* __restrict__ meang) {
    int b = blockIdx.x, c = threadIdx.x;
    float s = 0.f;
    for (int t = 0; t < 40; ++t) s += part[((size_t)b * 40 + t) * Cdim + c];
    meang[b * Cdim + c] = s * (1.0f / (float)Ntok);
}

// ---------------- per-row inverse norm of g (f32 source) ----------------
__global__ void invnorm_k(const float* __restrict__ g, float* __restrict__ invn) {
    int wid = threadIdx.x >> 6, lane = threadIdx.x & 63;
    int row = blockIdx.x * 4 + wid;
    const float* p = g + (size_t)row * Cdim;
    float ss = 0.f;
    #pragma unroll
    for (int i = lane; i < Cdim; i += 64) { float v = p[i]; ss += v * v; }
    #pragma unroll
    for (int o = 1; o < 64; o <<= 1) ss += __shfl_xor(ss, o);
    if (lane == 0) {
        float n = sqrtf(ss);
        invn[row] = 1.0f / fmaxf(n, 1e-12f);
    }
}

// ---------------- f32 -> f16 convert, optional per-token bias ----------------
__global__ void cvt_k(const float* __restrict__ src, const float* __restrict__ bias,
                      unsigned short* __restrict__ dst, int n4) {
    int i = blockIdx.x * 256 + threadIdx.x;
    if (i >= n4) return;
    float4 v = ((const float4*)src)[i];
    if (bias) {
        int b  = i / (Ntok * Cdim / 4);
        int c4 = (i & (Cdim / 4 - 1)) << 2;
        float4 bv = *(const float4*)&bias[b * Cdim + c4];
        v.x += bv.x; v.y += bv.y; v.z += bv.z; v.w += bv.w;
    }
    ushort4 h;
    h.x = f2h(v.x); h.y = f2h(v.y); h.z = f2h(v.z); h.w = f2h(v.w);
    ((ushort4*)dst)[i] = h;
}

// ---------------- batched 64x64-tiled u16 transpose ----------------
__global__ __launch_bounds__(256) void transpose1(
    const unsigned short* __restrict__ in, unsigned short* __restrict__ out,
    int R, int C, long inB, long outB)
{
    int z = blockIdx.z;
    in  += (size_t)z * inB;
    out += (size_t)z * outB;
    __shared__ unsigned short th[64][68];
    int r0 = blockIdx.y * 64, c0 = blockIdx.x * 64;
    int tr = threadIdx.x >> 4, tc = (threadIdx.x & 15) * 4;
    for (int rr = tr; rr < 64; rr += 16) {
        ushort4 h = *(const ushort4*)&in[(size_t)(r0 + rr) * C + c0 + tc];
        th[tc + 0][rr] = h.x; th[tc + 1][rr] = h.y; th[tc + 2][rr] = h.z; th[tc + 3][rr] = h.w;
    }
    __syncthreads();
    for (int cc = tr; cc < 64; cc += 16) {
        ushort4 h = *(const ushort4*)&th[cc][tc];
        *(ushort4*)&out[(size_t)(c0 + cc) * R + r0 + tc] = h;
    }
}

// ---------------- f16 MFMA GEMM (NT), 2-phase dbuf pipeline + XCD swizzle ------
// O = alpha * rs*cs * (A · B^T); A [M,ld], B [N,ld] k-contiguous f16;
// f32 accumulate. Tile BM=FM*32 x BN=FN*32, 4 waves as 2x2. Batched over z.
// Pipeline: STAGE(next) || compute(cur); one barrier per K-step (T3-minimum).
template<int FM, int FN>
__global__ __launch_bounds__(256) void mfma_gemm(
    const unsigned short* __restrict__ A, const unsigned short* __restrict__ B,
    float* __restrict__ Of32, unsigned short* __restrict__ Oh,
    int N, int K, int ld,
    long aB, long bB, long oB,
    float alpha, const float* __restrict__ rs, const float* __restrict__ cs, int sB)
{
    constexpr int BM = FM * 32, BN = FN * 32;
    constexpr int NCH = (BM + BN) / 16;   // 1KB staging chunks per K-step
    constexpr int CPW = NCH / 4;          // chunks per wave
    int z = blockIdx.z;

    // bijective XCD-aware swizzle of the tile index within this z-slice (m204)
    int gx = gridDim.x;
    int nwg = gx * gridDim.y;
    int orig = blockIdx.y * gx + blockIdx.x;
    int q = nwg >> 3, r = nwg & 7;
    int xcd = orig & 7, idx = orig >> 3;
    int wgid = (xcd < r ? xcd * (q + 1) : r * (q + 1) + (xcd - r) * q) + idx;
    int m0 = (wgid / gx) * BM, n0 = (wgid % gx) * BN;

    __shared__ __align__(16) unsigned short As[2][BM * 32];
    __shared__ __align__(16) unsigned short Bs[2][BN * 32];

    int tid  = threadIdx.x;
    int lane = tid & 63, wid = tid >> 6;
    int wm = (wid >> 1) * (FM * 16), wn = (wid & 1) * (FN * 16);

    // staging: lane -> (row = lane>>2 within 16-row chunk, swizzled 16B slot)
    int srow = lane >> 2;
    int sgc  = (lane & 3) ^ sfun(srow);

    const unsigned short* csrc[CPW];
    unsigned short* cdst0[CPW];
    unsigned short* cdst1[CPW];
    #pragma unroll
    for (int i = 0; i < CPW; ++i) {
        int c = wid * CPW + i;                 // wave-uniform
        if (c < BM / 16) {
            csrc[i]  = A + (size_t)z * aB + (size_t)(m0 + c * 16 + srow) * ld + sgc * 8;
            cdst0[i] = &As[0][c * 512];
            cdst1[i] = &As[1][c * 512];
        } else {
            int cb = c - BM / 16;
            csrc[i]  = B + (size_t)z * bB + (size_t)(n0 + cb * 16 + srow) * ld + sgc * 8;
            cdst0[i] = &Bs[0][cb * 512];
            cdst1[i] = &Bs[1][cb * 512];
        }
    }

    f32x4 acc[FM][FN] = {};
    int fr = lane & 15, kg = lane >> 4;

    const int nt = K / 32;
    // prologue: stage tile 0 into buffer 0
    #pragma unroll
    for (int i = 0; i < CPW; ++i) GLOAD_LDS16(csrc[i], cdst0[i]);
    __syncthreads();

    for (int t = 0; t < nt; ++t) {
        int cur = t & 1;
        // issue next tile's loads into the other buffer (stay in flight
        // across the compute; drained by the barrier's vmcnt at loop end)
        if (t + 1 < nt) {
            const int k1 = (t + 1) * 32;
            #pragma unroll
            for (int i = 0; i < CPW; ++i)
                GLOAD_LDS16(csrc[i] + k1, cur ? cdst0[i] : cdst1[i]);
        }
        // compute current tile
        const unsigned short* Ab = As[cur];
        const unsigned short* Bb = Bs[cur];
        half8 a[FM], b[FN];
        #pragma unroll
        for (int f = 0; f < FM; ++f) {
            int rr = wm + f * 16 + fr;
            a[f] = *(const half8*)&Ab[rr * 32 + ((kg ^ sfun(rr)) << 3)];
        }
        #pragma unroll
        for (int f = 0; f < FN; ++f) {
            int rr = wn + f * 16 + fr;
            b[f] = *(const half8*)&Bb[rr * 32 + ((kg ^ sfun(rr)) << 3)];
        }
        #pragma unroll
        for (int i = 0; i < FM; ++i)
            #pragma unroll
            for (int j = 0; j < FN; ++j)
                acc[i][j] = __builtin_amdgcn_mfma_f32_16x16x32_f16(a[i], b[j], acc[i][j], 0, 0, 0);
        __syncthreads();
    }

    float* O          = Of32 ? Of32 + (size_t)z * oB : nullptr;
    unsigned short* H = Oh   ? Oh   + (size_t)z * oB : nullptr;
    int fq = lane >> 4;
    #pragma unroll
    for (int i = 0; i < FM; ++i) {
        #pragma unroll
        for (int r4 = 0; r4 < 4; ++r4) {
            int gm = m0 + wm + i * 16 + fq * 4 + r4;
            float rf = alpha * (rs ? rs[(size_t)z * sB + gm] : 1.0f);
            #pragma unroll
            for (int j = 0; j < FN; ++j) {
                int gn = n0 + wn + j * 16 + fr;
                float v = acc[i][j][r4] * rf * (cs ? cs[(size_t)z * sB + gn] : 1.0f);
                size_t off = (size_t)gm * N + gn;
                if (O) O[off] = v;
                else   H[off] = f2h(v);
            }
        }
    }
}

// ---------------- in-place row softmax on f16 scores ----------------
__global__ __launch_bounds__(256) void softmax_h(unsigned short* __restrict__ P, int cols) {
    __shared__ float buf[1920];
    __shared__ float red[4];
    size_t row = blockIdx.x;
    unsigned short* p = P + row * (size_t)cols;
    int tid = threadIdx.x;
    int nq = cols >> 2;

    float lmax = -1e30f;
    for (int q = tid; q < nq; q += 256) {
        ushort4 h = ((const ushort4*)p)[q];
        float v0 = h2f(h.x), v1 = h2f(h.y), v2 = h2f(h.z), v3 = h2f(h.w);
        buf[q * 4 + 0] = v0; buf[q * 4 + 1] = v1;
        buf[q * 4 + 2] = v2; buf[q * 4 + 3] = v3;
        lmax = fmaxf(lmax, fmaxf(fmaxf(v0, v1), fmaxf(v2, v3)));
    }
    #pragma unroll
    for (int o = 1; o < 64; o <<= 1) lmax = fmaxf(lmax, __shfl_xor(lmax, o));
    if ((tid & 63) == 0) red[tid >> 6] = lmax;
    __syncthreads();
    float bmax = fmaxf(fmaxf(red[0], red[1]), fmaxf(red[2], red[3]));

    float lsum = 0.f;
    for (int c = tid; c < cols; c += 256) {
        float e = expf(buf[c] - bmax);
        buf[c] = e;
        lsum += e;
    }
    #pragma unroll
    for (int o = 1; o < 64; o <<= 1) lsum += __shfl_xor(lsum, o);
    __syncthreads();
    if ((tid & 63) == 0) red[tid >> 6] = lsum;
    __syncthreads();
    float inv = 1.0f / (red[0] + red[1] + red[2] + red[3]);

    for (int q = tid; q < nq; q += 256) {
        ushort4 h;
        h.x = f2h(buf[q * 4 + 0] * inv);
        h.y = f2h(buf[q * 4 + 1] * inv);
        h.z = f2h(buf[q * 4 + 2] * inv);
        h.w = f2h(buf[q * 4 + 3] * inv);
        ((ushort4*)p)[q] = h;
    }
}

// ---------------- launch ----------------
extern "C" void kernel_launch(void* const* d_in, const int* in_sizes, int n_in,
                              void* d_out, int out_size, void* d_ws, size_t ws_size,
                              hipStream_t stream) {
    (void)in_sizes; (void)n_in; (void)out_size; (void)ws_size;
    const float* x  = (const float*)d_in[0];
    const float* g  = (const float*)d_in[1];
    const float* Wq = (const float*)d_in[2];
    const float* Wg = (const float*)d_in[3];
    float* out = (float*)d_out;

    const size_t GE = (size_t)Mrows * Cdim;      // 7,864,320 elems
    char* ws = (char*)d_ws;
    size_t off = 0;
    auto alloc = [&](size_t bytes) { char* p = ws + off; off += (bytes + 255) & ~(size_t)255; return p; };

    float* meang = (float*)alloc(Bsz * Cdim * 4);
    float* part  = (float*)alloc(Bsz * 40 * Cdim * 4);
    float* invn  = (float*)alloc(Mrows * 4);
    unsigned short* gh   = (unsigned short*)alloc(GE * 2);            // g f16
    unsigned short* gTh  = (unsigned short*)alloc(GE * 2);            // [NBLK][512][192]
    unsigned short* qh   = (unsigned short*)alloc(GE * 2);            // q f16; reused as g2T
    unsigned short* wqh  = (unsigned short*)alloc((size_t)Cdim * Cdim * 2);
    unsigned short* wgh  = (unsigned short*)alloc((size_t)Cdim * Cdim * 2);
    unsigned short* rqh  = (unsigned short*)alloc(GE * 2);
    unsigned short* rgh  = (unsigned short*)alloc(GE * 2);
    unsigned short* g2h  = (unsigned short*)alloc(GE * 2);
    unsigned short* sbh  = (unsigned short*)alloc((size_t)NBLK * BLK * BLK * 2);
    unsigned short* s2h  = (unsigned short*)alloc((size_t)Bsz * Ntok * Ntok * 2);  // 59 MB
    unsigned short* g2Th = qh;                                        // [Bsz][512][1920]

    // 1. token mean; per-row inv norms (f32 sources)
    mean_partial<<<dim3(Bsz, 40), 512, 0, stream>>>(g, part);
    mean_final<<<Bsz, 512, 0, stream>>>(part, meang);
    invnorm_k<<<Mrows / 4, 256, 0, stream>>>(g, invn);

    // 2. f16 conversions
    cvt_k<<<(int)(GE / 4 + 255) / 256, 256, 0, stream>>>(g, nullptr, gh, (int)(GE / 4));
    cvt_k<<<(int)(GE / 4 + 255) / 256, 256, 0, stream>>>(x, meang, qh, (int)(GE / 4));
    cvt_k<<<(Cdim * Cdim / 4) / 256, 256, 0, stream>>>(Wq, nullptr, wqh, Cdim * Cdim / 4);
    cvt_k<<<(Cdim * Cdim / 4) / 256, 256, 0, stream>>>(Wg, nullptr, wgh, Cdim * Cdim / 4);

    // 2b. gT: per 192-block transpose  [NBLK][512][192]
    transpose1<<<dim3(Cdim / 64, BLK / 64, NBLK), 256, 0, stream>>>(
        gh, gTh, BLK, Cdim, (long)BLK * Cdim, (long)Cdim * BLK);

    // 3. rel_q = q @ Wq^T -> f16  [15360,512]  (64x64 tiles, 1920 blocks)
    mfma_gemm<2, 2><<<dim3(Cdim / 64, Mrows / 64), 256, 0, stream>>>(
        qh, wqh, nullptr, rqh, Cdim, Cdim, Cdim, 0, 0, 0, 1.0f, nullptr, nullptr, 0);

    // 4. block scores = (g·g^T)*invn_i*invn_j*SCALE -> f16  [80][192][192]  (720 blocks)
    mfma_gemm<2, 2><<<dim3(3, 3, NBLK), 256, 0, stream>>>(
        gh, gh, nullptr, sbh, BLK, Cdim, Cdim,
        (long)BLK * Cdim, (long)BLK * Cdim, (long)BLK * BLK,
        SCALE, invn, invn, BLK);

    // 5. block softmax in place
    softmax_h<<<NBLK * BLK, 256, 0, stream>>>(sbh, BLK);

    // 6. g2 = attn · (gT)^T -> f16  [80][192][512]  (64x64 tiles, 1920 blocks)
    mfma_gemm<2, 2><<<dim3(Cdim / 64, BLK / 64, NBLK), 256, 0, stream>>>(
        sbh, gTh, nullptr, g2h, Cdim, BLK, BLK,
        (long)BLK * BLK, (long)Cdim * BLK, (long)BLK * Cdim,
        1.0f, nullptr, nullptr, 0);

    // 6b. g2T: per-batch transpose  [Bsz][512][1920]  (into dead q buffer)
    transpose1<<<dim3(Cdim / 64, Ntok / 64, Bsz), 256, 0, stream>>>(
        g2h, g2Th, Ntok, Cdim, (long)Ntok * Cdim, (long)Cdim * Ntok);

    // 7. rel_g = g2 @ Wg^T -> f16  [15360,512]  (64x64 tiles, 1920 blocks)
    mfma_gemm<2, 2><<<dim3(Cdim / 64, Mrows / 64), 256, 0, stream>>>(
        g2h, wgh, nullptr, rgh, Cdim, Cdim, Cdim, 0, 0, 0, 1.0f, nullptr, nullptr, 0);

    // 8. global scores = rel_q @ rel_g^T * SCALE -> f16  [8][1920][1920]  (1800 blocks)
    mfma_gemm<4, 4><<<dim3(Ntok / 128, Ntok / 128, Bsz), 256, 0, stream>>>(
        rqh, rgh, nullptr, s2h, Ntok, Cdim, Cdim,
        (long)Ntok * Cdim, (long)Ntok * Cdim, (long)Ntok * Ntok,
        SCALE, nullptr, nullptr, 0);

    // 9. global softmax in place  (15360 rows of 1920)
    softmax_h<<<Bsz * Ntok, 256, 0, stream>>>(s2h, Ntok);

    // 10. out = attn2 · (g2T)^T -> f32  [8][1920][512]  (64x64 tiles, 1920 blocks)
    mfma_gemm<2, 2><<<dim3(Cdim / 64, Ntok / 64, Bsz), 256, 0, stream>>>(
        s2h, g2Th, out, nullptr, Cdim, Ntok, Ntok,
        (long)Ntok * Ntok, (long)Cdim * Ntok, (long)Ntok * Cdim,
        1.0f, nullptr, nullptr, 0);
}

// Round 10
// 282.109 us; speedup vs baseline: 1.0909x; 1.0909x over previous
//
#include <hip/hip_runtime.h>
#include <math.h>

// Problem constants
constexpr int Bsz  = 8;
constexpr int Ntok = 1920;
constexpr int Cdim = 512;
constexpr int BLK  = 192;
constexpr int Mrows = Bsz * Ntok;      // 15360
constexpr int NBLK  = Mrows / BLK;     // 80
constexpr float SCALE = 0.02209708691207961f;  // 2048^-0.5

typedef _Float16 half8 __attribute__((ext_vector_type(8)));
typedef float    f32x4 __attribute__((ext_vector_type(4)));

#define GLOAD_LDS16(gp, lp) __builtin_amdgcn_global_load_lds( \
    (const __attribute__((address_space(1))) void*)(gp),      \
    (__attribute__((address_space(3))) void*)(lp), 16, 0, 0)

// ---- f16 helpers ----
__device__ inline unsigned short f2h(float f) {
    _Float16 h = (_Float16)f;
    return __builtin_bit_cast(unsigned short, h);
}
__device__ inline float h2f(unsigned short u) {
    return (float)__builtin_bit_cast(_Float16, u);
}

// slot swizzle (involution, applied to global source chunk AND ds_read chunk)
template<int BK> __device__ inline int smask(int r) {
    return (BK == 32) ? ((r & 3) ^ ((r >> 2) & 3)) : (r & 7);
}

// ---------------- token mean (two-stage) ----------------
__global__ void mean_partial(const float* __restrict__ g, float* __restrict__ part) {
    int b = blockIdx.x, t = blockIdx.y, c = threadIdx.x;
    const float* p = g + ((size_t)b * Ntok + (size_t)t * 48) * Cdim + c;
    float s = 0.f;
    #pragma unroll 4
    for (int n = 0; n < 48; ++n) s += p[(size_t)n * Cdim];
    part[((size_t)b * 40 + t) * Cdim + c] = s;
}

__global__ void mean_final(const float* __restrict__ part, float* __restrict__ meang) {
    int b = blockIdx.x, c = threadIdx.x;
    float s = 0.f;
    for (int t = 0; t < 40; ++t) s += part[((size_t)b * 40 + t) * Cdim + c];
    meang[b * Cdim + c] = s * (1.0f / (float)Ntok);
}

// ---------------- per-row inverse norm of g (f32 source) ----------------
__global__ void invnorm_k(const float* __restrict__ g, float* __restrict__ invn) {
    int wid = threadIdx.x >> 6, lane = threadIdx.x & 63;
    int row = blockIdx.x * 4 + wid;
    const float* p = g + (size_t)row * Cdim;
    float ss = 0.f;
    #pragma unroll
    for (int i = lane; i < Cdim; i += 64) { float v = p[i]; ss += v * v; }
    #pragma unroll
    for (int o = 1; o < 64; o <<= 1) ss += __shfl_xor(ss, o);
    if (lane == 0) {
        float n = sqrtf(ss);
        invn[row] = 1.0f / fmaxf(n, 1e-12f);
    }
}

// ---------------- f32 -> f16 convert, optional per-token bias ----------------
__global__ void cvt_k(const float* __restrict__ src, const float* __restrict__ bias,
                      unsigned short* __restrict__ dst, int n4) {
    int i = blockIdx.x * 256 + threadIdx.x;
    if (i >= n4) return;
    float4 v = ((const float4*)src)[i];
    if (bias) {
        int b  = i / (Ntok * Cdim / 4);
        int c4 = (i & (Cdim / 4 - 1)) << 2;
        float4 bv = *(const float4*)&bias[b * Cdim + c4];
        v.x += bv.x; v.y += bv.y; v.z += bv.z; v.w += bv.w;
    }
    ushort4 h;
    h.x = f2h(v.x); h.y = f2h(v.y); h.z = f2h(v.z); h.w = f2h(v.w);
    ((ushort4*)dst)[i] = h;
}

// ---------------- batched 64x64-tiled u16 transpose ----------------
__global__ __launch_bounds__(256) void transpose1(
    const unsigned short* __restrict__ in, unsigned short* __restrict__ out,
    int R, int C, long inB, long outB)
{
    int z = blockIdx.z;
    in  += (size_t)z * inB;
    out += (size_t)z * outB;
    __shared__ unsigned short th[64][68];
    int r0 = blockIdx.y * 64, c0 = blockIdx.x * 64;
    int tr = threadIdx.x >> 4, tc = (threadIdx.x & 15) * 4;
    for (int rr = tr; rr < 64; rr += 16) {
        ushort4 h = *(const ushort4*)&in[(size_t)(r0 + rr) * C + c0 + tc];
        th[tc + 0][rr] = h.x; th[tc + 1][rr] = h.y; th[tc + 2][rr] = h.z; th[tc + 3][rr] = h.w;
    }
    __syncthreads();
    for (int cc = tr; cc < 64; cc += 16) {
        ushort4 h = *(const ushort4*)&th[cc][tc];
        *(ushort4*)&out[(size_t)(c0 + cc) * R + r0 + tc] = h;
    }
}

// ---------------- f16 MFMA GEMM (NT), 2-phase dbuf + XCD swizzle, param BK ------
// O = alpha * rs*cs * (A · B^T); A [M,ld], B [N,ld] k-contiguous f16; f32 accum.
// Tile BM=FM*32 x BN=FN*32, 4 waves as 2x2; K-step BK (32 or 64).
// LDS row-major [row][BK]; 1KB chunk = (512/BK) rows; slot XOR-swizzle both sides.
template<int FM, int FN, int BK>
__global__ __launch_bounds__(256) void mfma_gemm(
    const unsigned short* __restrict__ A, const unsigned short* __restrict__ B,
    float* __restrict__ Of32, unsigned short* __restrict__ Oh,
    int N, int K, int ld,
    long aB, long bB, long oB,
    float alpha, const float* __restrict__ rs, const float* __restrict__ cs, int sB)
{
    constexpr int BM = FM * 32, BN = FN * 32;
    constexpr int RPC = 512 / BK;          // rows per 1KB chunk
    constexpr int LPR = BK / 8;            // lanes per row (16B slots per row)
    constexpr int NCH = (BM + BN) / RPC;   // 1KB chunks per K-step
    constexpr int CPW = NCH / 4;           // chunks per wave
    int z = blockIdx.z;

    // bijective XCD-aware swizzle of tile index within this z-slice (m204)
    int gx = gridDim.x;
    int nwg = gx * gridDim.y;
    int orig = blockIdx.y * gx + blockIdx.x;
    int q = nwg >> 3, r = nwg & 7;
    int xcd = orig & 7, idx = orig >> 3;
    int wgid = (xcd < r ? xcd * (q + 1) : r * (q + 1) + (xcd - r) * q) + idx;
    int m0 = (wgid / gx) * BM, n0 = (wgid % gx) * BN;

    __shared__ __align__(16) unsigned short As[2][BM * BK];
    __shared__ __align__(16) unsigned short Bs[2][BN * BK];

    int tid  = threadIdx.x;
    int lane = tid & 63, wid = tid >> 6;
    int wm = (wid >> 1) * (FM * 16), wn = (wid & 1) * (FN * 16);

    // staging: lane -> (row within chunk, swizzled 16B slot)
    int srow = lane / LPR;
    int sgc  = (lane % LPR) ^ smask<BK>(srow);

    const unsigned short* csrc[CPW];
    unsigned short* cdst0[CPW];
    unsigned short* cdst1[CPW];
    #pragma unroll
    for (int i = 0; i < CPW; ++i) {
        int c = wid * CPW + i;                 // wave-uniform chunk id
        if (c < BM / RPC) {
            csrc[i]  = A + (size_t)z * aB + (size_t)(m0 + c * RPC + srow) * ld + sgc * 8;
            cdst0[i] = &As[0][c * 512];
            cdst1[i] = &As[1][c * 512];
        } else {
            int cb = c - BM / RPC;
            csrc[i]  = B + (size_t)z * bB + (size_t)(n0 + cb * RPC + srow) * ld + sgc * 8;
            cdst0[i] = &Bs[0][cb * 512];
            cdst1[i] = &Bs[1][cb * 512];
        }
    }

    f32x4 acc[FM][FN] = {};
    int fr = lane & 15, kq = lane >> 4;    // fragment row / k-quarter

    const int nt = K / BK;
    #pragma unroll
    for (int i = 0; i < CPW; ++i) GLOAD_LDS16(csrc[i], cdst0[i]);
    __syncthreads();

    for (int t = 0; t < nt; ++t) {
        int cur = t & 1;
        if (t + 1 < nt) {
            const int k1 = (t + 1) * BK;
            #pragma unroll
            for (int i = 0; i < CPW; ++i)
                GLOAD_LDS16(csrc[i] + k1, cur ? cdst0[i] : cdst1[i]);
        }
        const unsigned short* Ab = As[cur];
        const unsigned short* Bb = Bs[cur];
        #pragma unroll
        for (int ks = 0; ks < BK / 32; ++ks) {
            int slot = ks * 4 + kq;            // 16B slot within the row
            half8 a[FM], b[FN];
            #pragma unroll
            for (int f = 0; f < FM; ++f) {
                int rr = wm + f * 16 + fr;
                a[f] = *(const half8*)&Ab[rr * BK + ((slot ^ smask<BK>(rr)) << 3)];
            }
            #pragma unroll
            for (int f = 0; f < FN; ++f) {
                int rr = wn + f * 16 + fr;
                b[f] = *(const half8*)&Bb[rr * BK + ((slot ^ smask<BK>(rr)) << 3)];
            }
            #pragma unroll
            for (int i = 0; i < FM; ++i)
                #pragma unroll
                for (int j = 0; j < FN; ++j)
                    acc[i][j] = __builtin_amdgcn_mfma_f32_16x16x32_f16(a[i], b[j], acc[i][j], 0, 0, 0);
        }
        __syncthreads();
    }

    float* O          = Of32 ? Of32 + (size_t)z * oB : nullptr;
    unsigned short* H = Oh   ? Oh   + (size_t)z * oB : nullptr;
    int fq = lane >> 4;
    #pragma unroll
    for (int i = 0; i < FM; ++i) {
        #pragma unroll
        for (int r4 = 0; r4 < 4; ++r4) {
            int gm = m0 + wm + i * 16 + fq * 4 + r4;
            float rf = alpha * (rs ? rs[(size_t)z * sB + gm] : 1.0f);
            #pragma unroll
            for (int j = 0; j < FN; ++j) {
                int gn = n0 + wn + j * 16 + fr;
                float v = acc[i][j][r4] * rf * (cs ? cs[(size_t)z * sB + gn] : 1.0f);
                size_t off = (size_t)gm * N + gn;
                if (O) O[off] = v;
                else   H[off] = f2h(v);
            }
        }
    }
}

// ---------------- in-place row softmax on f16 scores ----------------
__global__ __launch_bounds__(256) void softmax_h(unsigned short* __restrict__ P, int cols) {
    __shared__ float buf[1920];
    __shared__ float red[4];
    size_t row = blockIdx.x;
    unsigned short* p = P + row * (size_t)cols;
    int tid = threadIdx.x;
    int nq = cols >> 2;

    float lmax = -1e30f;
    for (int q = tid; q < nq; q += 256) {
        ushort4 h = ((const ushort4*)p)[q];
        float v0 = h2f(h.x), v1 = h2f(h.y), v2 = h2f(h.z), v3 = h2f(h.w);
        buf[q * 4 + 0] = v0; buf[q * 4 + 1] = v1;
        buf[q * 4 + 2] = v2; buf[q * 4 + 3] = v3;
        lmax = fmaxf(lmax, fmaxf(fmaxf(v0, v1), fmaxf(v2, v3)));
    }
    #pragma unroll
    for (int o = 1; o < 64; o <<= 1) lmax = fmaxf(lmax, __shfl_xor(lmax, o));
    if ((tid & 63) == 0) red[tid >> 6] = lmax;
    __syncthreads();
    float bmax = fmaxf(fmaxf(red[0], red[1]), fmaxf(red[2], red[3]));

    float lsum = 0.f;
    for (int c = tid; c < cols; c += 256) {
        float e = expf(buf[c] - bmax);
        buf[c] = e;
        lsum += e;
    }
    #pragma unroll
    for (int o = 1; o < 64; o <<= 1) lsum += __shfl_xor(lsum, o);
    __syncthreads();
    if ((tid & 63) == 0) red[tid >> 6] = lsum;
    __syncthreads();
    float inv = 1.0f / (red[0] + red[1] + red[2] + red[3]);

    for (int q = tid; q < nq; q += 256) {
        ushort4 h;
        h.x = f2h(buf[q * 4 + 0] * inv);
        h.y = f2h(buf[q * 4 + 1] * inv);
        h.z = f2h(buf[q * 4 + 2] * inv);
        h.w = f2h(buf[q * 4 + 3] * inv);
        ((ushort4*)p)[q] = h;
    }
}

// ---------------- launch ----------------
extern "C" void kernel_launch(void* const* d_in, const int* in_sizes, int n_in,
                              void* d_out, int out_size, void* d_ws, size_t ws_size,
                              hipStream_t stream) {
    (void)in_sizes; (void)n_in; (void)out_size; (void)ws_size;
    const float* x  = (const float*)d_in[0];
    const float* g  = (const float*)d_in[1];
    const float* Wq = (const float*)d_in[2];
    const float* Wg = (const float*)d_in[3];
    float* out = (float*)d_out;

    const size_t GE = (size_t)Mrows * Cdim;      // 7,864,320 elems
    char* ws = (char*)d_ws;
    size_t off = 0;
    auto alloc = [&](size_t bytes) { char* p = ws + off; off += (bytes + 255) & ~(size_t)255; return p; };

    float* meang = (float*)alloc(Bsz * Cdim * 4);
    float* part  = (float*)alloc(Bsz * 40 * Cdim * 4);
    float* invn  = (float*)alloc(Mrows * 4);
    unsigned short* gh   = (unsigned short*)alloc(GE * 2);            // g f16
    unsigned short* gTh  = (unsigned short*)alloc(GE * 2);            // [NBLK][512][192]
    unsigned short* qh   = (unsigned short*)alloc(GE * 2);            // q f16; reused as g2T
    unsigned short* wqh  = (unsigned short*)alloc((size_t)Cdim * Cdim * 2);
    unsigned short* wgh  = (unsigned short*)alloc((size_t)Cdim * Cdim * 2);
    unsigned short* rqh  = (unsigned short*)alloc(GE * 2);
    unsigned short* rgh  = (unsigned short*)alloc(GE * 2);
    unsigned short* g2h  = (unsigned short*)alloc(GE * 2);
    unsigned short* sbh  = (unsigned short*)alloc((size_t)NBLK * BLK * BLK * 2);
    unsigned short* s2h  = (unsigned short*)alloc((size_t)Bsz * Ntok * Ntok * 2);  // 59 MB
    unsigned short* g2Th = qh;                                        // [Bsz][512][1920]

    // 1. token mean; per-row inv norms (f32 sources)
    mean_partial<<<dim3(Bsz, 40), 512, 0, stream>>>(g, part);
    mean_final<<<Bsz, 512, 0, stream>>>(part, meang);
    invnorm_k<<<Mrows / 4, 256, 0, stream>>>(g, invn);

    // 2. f16 conversions
    cvt_k<<<(int)(GE / 4 + 255) / 256, 256, 0, stream>>>(g, nullptr, gh, (int)(GE / 4));
    cvt_k<<<(int)(GE / 4 + 255) / 256, 256, 0, stream>>>(x, meang, qh, (int)(GE / 4));
    cvt_k<<<(Cdim * Cdim / 4) / 256, 256, 0, stream>>>(Wq, nullptr, wqh, Cdim * Cdim / 4);
    cvt_k<<<(Cdim * Cdim / 4) / 256, 256, 0, stream>>>(Wg, nullptr, wgh, Cdim * Cdim / 4);

    // 2b. gT: per 192-block transpose  [NBLK][512][192]
    transpose1<<<dim3(Cdim / 64, BLK / 64, NBLK), 256, 0, stream>>>(
        gh, gTh, BLK, Cdim, (long)BLK * Cdim, (long)Cdim * BLK);

    // 3. rel_q = q @ Wq^T -> f16  [15360,512]  (<2,4> BK64, 960 blocks)
    mfma_gemm<2, 4, 64><<<dim3(Cdim / 128, Mrows / 64), 256, 0, stream>>>(
        qh, wqh, nullptr, rqh, Cdim, Cdim, Cdim, 0, 0, 0, 1.0f, nullptr, nullptr, 0);

    // 4. block scores = (g·g^T)*invn_i*invn_j*SCALE -> f16  [80][192][192]  (720 blocks)
    mfma_gemm<2, 2, 32><<<dim3(3, 3, NBLK), 256, 0, stream>>>(
        gh, gh, nullptr, sbh, BLK, Cdim, Cdim,
        (long)BLK * Cdim, (long)BLK * Cdim, (long)BLK * BLK,
        SCALE, invn, invn, BLK);

    // 5. block softmax in place
    softmax_h<<<NBLK * BLK, 256, 0, stream>>>(sbh, BLK);

    // 6. g2 = attn · (gT)^T -> f16  [80][192][512]  (<2,4> BK64, 960 blocks, K=192)
    mfma_gemm<2, 4, 64><<<dim3(Cdim / 128, BLK / 64, NBLK), 256, 0, stream>>>(
        sbh, gTh, nullptr, g2h, Cdim, BLK, BLK,
        (long)BLK * BLK, (long)Cdim * BLK, (long)BLK * Cdim,
        1.0f, nullptr, nullptr, 0);

    // 6b. g2T: per-batch transpose  [Bsz][512][1920]  (into dead q buffer)
    transpose1<<<dim3(Cdim / 64, Ntok / 64, Bsz), 256, 0, stream>>>(
        g2h, g2Th, Ntok, Cdim, (long)Ntok * Cdim, (long)Cdim * Ntok);

    // 7. rel_g = g2 @ Wg^T -> f16  [15360,512]  (<2,4> BK64, 960 blocks)
    mfma_gemm<2, 4, 64><<<dim3(Cdim / 128, Mrows / 64), 256, 0, stream>>>(
        g2h, wgh, nullptr, rgh, Cdim, Cdim, Cdim, 0, 0, 0, 1.0f, nullptr, nullptr, 0);

    // 8. global scores = rel_q @ rel_g^T * SCALE -> f16  [8][1920][1920]  (<4,4> BK32, 1800 blocks)
    mfma_gemm<4, 4, 32><<<dim3(Ntok / 128, Ntok / 128, Bsz), 256, 0, stream>>>(
        rqh, rgh, nullptr, s2h, Ntok, Cdim, Cdim,
        (long)Ntok * Cdim, (long)Ntok * Cdim, (long)Ntok * Ntok,
        SCALE, nullptr, nullptr, 0);

    // 9. global softmax in place  (15360 rows of 1920)
    softmax_h<<<Bsz * Ntok, 256, 0, stream>>>(s2h, Ntok);

    // 10. out = attn2 · (g2T)^T -> f32  [8][1920][512]  (<2,4> BK64, 960 blocks, K=1920)
    mfma_gemm<2, 4, 64><<<dim3(Cdim / 128, Ntok / 64, Bsz), 256, 0, stream>>>(
        s2h, g2Th, out, nullptr, Cdim, Ntok, Ntok,
        (long)Ntok * Ntok, (long)Cdim * Ntok, (long)Ntok * Cdim,
        1.0f, nullptr, nullptr, 0);
}

// Round 11
// 271.279 us; speedup vs baseline: 1.1345x; 1.0399x over previous
//
#include <hip/hip_runtime.h>
#include <math.h>

// Problem constants
constexpr int Bsz  = 8;
constexpr int Ntok = 1920;
constexpr int Cdim = 512;
constexpr int BLK  = 192;
constexpr int Mrows = Bsz * Ntok;      // 15360
constexpr int NBLK  = Mrows / BLK;     // 80
constexpr float SCALE = 0.02209708691207961f;  // 2048^-0.5

typedef _Float16 half8 __attribute__((ext_vector_type(8)));
typedef float    f32x4 __attribute__((ext_vector_type(4)));

#define GLOAD_LDS16(gp, lp) __builtin_amdgcn_global_load_lds( \
    (const __attribute__((address_space(1))) void*)(gp),      \
    (__attribute__((address_space(3))) void*)(lp), 16, 0, 0)

// ---- f16 helpers ----
__device__ inline unsigned short f2h(float f) {
    _Float16 h = (_Float16)f;
    return __builtin_bit_cast(unsigned short, h);
}
__device__ inline float h2f(unsigned short u) {
    return (float)__builtin_bit_cast(_Float16, u);
}

// slot swizzle (involution, applied to global source chunk AND ds_read chunk)
template<int BK> __device__ inline int smask(int r) {
    return (BK == 32) ? ((r & 3) ^ ((r >> 2) & 3)) : (r & 7);
}

// counted vmcnt wait (T4): leave N loads in flight
template<int N> __device__ __forceinline__ void vm_wait() {
    if constexpr (N == 0)      asm volatile("s_waitcnt vmcnt(0)" ::: "memory");
    else if constexpr (N == 2) asm volatile("s_waitcnt vmcnt(2)" ::: "memory");
    else if constexpr (N == 4) asm volatile("s_waitcnt vmcnt(4)" ::: "memory");
    else if constexpr (N == 6) asm volatile("s_waitcnt vmcnt(6)" ::: "memory");
    else                       asm volatile("s_waitcnt vmcnt(8)" ::: "memory");
}

// ---------------- token mean (two-stage) ----------------
__global__ void mean_partial(const float* __restrict__ g, float* __restrict__ part) {
    int b = blockIdx.x, t = blockIdx.y, c = threadIdx.x;
    const float* p = g + ((size_t)b * Ntok + (size_t)t * 48) * Cdim + c;
    float s = 0.f;
    #pragma unroll 4
    for (int n = 0; n < 48; ++n) s += p[(size_t)n * Cdim];
    part[((size_t)b * 40 + t) * Cdim + c] = s;
}

__global__ void mean_final(const float* __restrict__ part, float* __restrict__ meang) {
    int b = blockIdx.x, c = threadIdx.x;
    float s = 0.f;
    for (int t = 0; t < 40; ++t) s += part[((size_t)b * 40 + t) * Cdim + c];
    meang[b * Cdim + c] = s * (1.0f / (float)Ntok);
}

// ---------------- per-row inverse norm of g (f32 source) ----------------
__global__ void invnorm_k(const float* __restrict__ g, float* __restrict__ invn) {
    int wid = threadIdx.x >> 6, lane = threadIdx.x & 63;
    int row = blockIdx.x * 4 + wid;
    const float* p = g + (size_t)row * Cdim;
    float ss = 0.f;
    #pragma unroll
    for (int i = lane; i < Cdim; i += 64) { float v = p[i]; ss += v * v; }
    #pragma unroll
    for (int o = 1; o < 64; o <<= 1) ss += __shfl_xor(ss, o);
    if (lane == 0) {
        float n = sqrtf(ss);
        invn[row] = 1.0f / fmaxf(n, 1e-12f);
    }
}

// ---------------- f32 -> f16 convert, optional per-token bias ----------------
__global__ void cvt_k(const float* __restrict__ src, const float* __restrict__ bias,
                      unsigned short* __restrict__ dst, int n4) {
    int i = blockIdx.x * 256 + threadIdx.x;
    if (i >= n4) return;
    float4 v = ((const float4*)src)[i];
    if (bias) {
        int b  = i / (Ntok * Cdim / 4);
        int c4 = (i & (Cdim / 4 - 1)) << 2;
        float4 bv = *(const float4*)&bias[b * Cdim + c4];
        v.x += bv.x; v.y += bv.y; v.z += bv.z; v.w += bv.w;
    }
    ushort4 h;
    h.x = f2h(v.x); h.y = f2h(v.y); h.z = f2h(v.z); h.w = f2h(v.w);
    ((ushort4*)dst)[i] = h;
}

// ---------------- batched 64x64-tiled u16 transpose ----------------
__global__ __launch_bounds__(256) void transpose1(
    const unsigned short* __restrict__ in, unsigned short* __restrict__ out,
    int R, int C, long inB, long outB)
{
    int z = blockIdx.z;
    in  += (size_t)z * inB;
    out += (size_t)z * outB;
    __shared__ unsigned short th[64][68];
    int r0 = blockIdx.y * 64, c0 = blockIdx.x * 64;
    int tr = threadIdx.x >> 4, tc = (threadIdx.x & 15) * 4;
    for (int rr = tr; rr < 64; rr += 16) {
        ushort4 h = *(const ushort4*)&in[(size_t)(r0 + rr) * C + c0 + tc];
        th[tc + 0][rr] = h.x; th[tc + 1][rr] = h.y; th[tc + 2][rr] = h.z; th[tc + 3][rr] = h.w;
    }
    __syncthreads();
    for (int cc = tr; cc < 64; cc += 16) {
        ushort4 h = *(const ushort4*)&th[cc][tc];
        *(ushort4*)&out[(size_t)(c0 + cc) * R + r0 + tc] = h;
    }
}

// ---------------- f16 MFMA GEMM (NT), depth-2 counted-vmcnt pipeline ------------
// O = alpha * rs*cs * (A · B^T); A [M,ld], B [N,ld] k-contiguous f16; f32 accum.
// Tile BM=FM*32 x BN=FN*32, 4 waves as 2x2; K-step BK (32 or 64).
// T4 pipeline: stage t+2 after compute(t); barrier waits only own-tile loads
// (vmcnt(CPW)) -- next tile's CPW loads stay in flight across the barrier.
template<int FM, int FN, int BK>
__global__ __launch_bounds__(256) void mfma_gemm(
    const unsigned short* __restrict__ A, const unsigned short* __restrict__ B,
    float* __restrict__ Of32, unsigned short* __restrict__ Oh,
    int N, int K, int ld,
    long aB, long bB, long oB,
    float alpha, const float* __restrict__ rs, const float* __restrict__ cs, int sB)
{
    constexpr int BM = FM * 32, BN = FN * 32;
    constexpr int RPC = 512 / BK;          // rows per 1KB chunk
    constexpr int LPR = BK / 8;            // lanes per row (16B slots per row)
    constexpr int NCH = (BM + BN) / RPC;   // 1KB chunks per K-step
    constexpr int CPW = NCH / 4;           // chunks per wave
    int z = blockIdx.z;

    // bijective XCD-aware swizzle of tile index within this z-slice (m204)
    int gx = gridDim.x;
    int nwg = gx * gridDim.y;
    int orig = blockIdx.y * gx + blockIdx.x;
    int q = nwg >> 3, r = nwg & 7;
    int xcd = orig & 7, idx = orig >> 3;
    int wgid = (xcd < r ? xcd * (q + 1) : r * (q + 1) + (xcd - r) * q) + idx;
    int m0 = (wgid / gx) * BM, n0 = (wgid % gx) * BN;

    __shared__ __align__(16) unsigned short As[2][BM * BK];
    __shared__ __align__(16) unsigned short Bs[2][BN * BK];

    int tid  = threadIdx.x;
    int lane = tid & 63, wid = tid >> 6;
    int wm = (wid >> 1) * (FM * 16), wn = (wid & 1) * (FN * 16);

    // staging: lane -> (row within chunk, swizzled 16B slot)
    int srow = lane / LPR;
    int sgc  = (lane % LPR) ^ smask<BK>(srow);

    const unsigned short* csrc[CPW];
    unsigned short* cdst0[CPW];
    unsigned short* cdst1[CPW];
    #pragma unroll
    for (int i = 0; i < CPW; ++i) {
        int c = wid * CPW + i;                 // wave-uniform chunk id
        if (c < BM / RPC) {
            csrc[i]  = A + (size_t)z * aB + (size_t)(m0 + c * RPC + srow) * ld + sgc * 8;
            cdst0[i] = &As[0][c * 512];
            cdst1[i] = &As[1][c * 512];
        } else {
            int cb = c - BM / RPC;
            csrc[i]  = B + (size_t)z * bB + (size_t)(n0 + cb * RPC + srow) * ld + sgc * 8;
            cdst0[i] = &Bs[0][cb * 512];
            cdst1[i] = &Bs[1][cb * 512];
        }
    }

    f32x4 acc[FM][FN] = {};
    int fr = lane & 15, kq = lane >> 4;    // fragment row / k-quarter

    const int nt = K / BK;
    // prologue: stage tiles 0 and 1 (depth-2; all shapes here have nt >= 2)
    #pragma unroll
    for (int i = 0; i < CPW; ++i) GLOAD_LDS16(csrc[i], cdst0[i]);
    #pragma unroll
    for (int i = 0; i < CPW; ++i) GLOAD_LDS16(csrc[i] + BK, cdst1[i]);

    for (int t = 0; t < nt; ++t) {
        int cur = t & 1;
        // wait for tile t's loads (leave tile t+1's CPW in flight), then sync
        if (t + 1 < nt) vm_wait<CPW>(); else vm_wait<0>();
        __builtin_amdgcn_sched_barrier(0);
        __builtin_amdgcn_s_barrier();
        __builtin_amdgcn_sched_barrier(0);

        const unsigned short* Ab = As[cur];
        const unsigned short* Bb = Bs[cur];
        #pragma unroll
        for (int ks = 0; ks < BK / 32; ++ks) {
            int slot = ks * 4 + kq;            // 16B slot within the row
            half8 a[FM], b[FN];
            #pragma unroll
            for (int f = 0; f < FM; ++f) {
                int rr = wm + f * 16 + fr;
                a[f] = *(const half8*)&Ab[rr * BK + ((slot ^ smask<BK>(rr)) << 3)];
            }
            #pragma unroll
            for (int f = 0; f < FN; ++f) {
                int rr = wn + f * 16 + fr;
                b[f] = *(const half8*)&Bb[rr * BK + ((slot ^ smask<BK>(rr)) << 3)];
            }
            #pragma unroll
            for (int i = 0; i < FM; ++i)
                #pragma unroll
                for (int j = 0; j < FN; ++j)
                    acc[i][j] = __builtin_amdgcn_mfma_f32_16x16x32_f16(a[i], b[j], acc[i][j], 0, 0, 0);
        }

        // all waves done reading buf[cur] before tile t+2 is staged into it
        __builtin_amdgcn_sched_barrier(0);
        __builtin_amdgcn_s_barrier();
        if (t + 2 < nt) {
            const int k2 = (t + 2) * BK;
            #pragma unroll
            for (int i = 0; i < CPW; ++i)
                GLOAD_LDS16(csrc[i] + k2, cur ? cdst1[i] : cdst0[i]);
        }
    }

    float* O          = Of32 ? Of32 + (size_t)z * oB : nullptr;
    unsigned short* H = Oh   ? Oh   + (size_t)z * oB : nullptr;
    int fq = lane >> 4;
    #pragma unroll
    for (int i = 0; i < FM; ++i) {
        #pragma unroll
        for (int r4 = 0; r4 < 4; ++r4) {
            int gm = m0 + wm + i * 16 + fq * 4 + r4;
            float rf = alpha * (rs ? rs[(size_t)z * sB + gm] : 1.0f);
            #pragma unroll
            for (int j = 0; j < FN; ++j) {
                int gn = n0 + wn + j * 16 + fr;
                float v = acc[i][j][r4] * rf * (cs ? cs[(size_t)z * sB + gn] : 1.0f);
                size_t off = (size_t)gm * N + gn;
                if (O) O[off] = v;
                else   H[off] = f2h(v);
            }
        }
    }
}

// ---------------- in-place row softmax on f16 scores ----------------
__global__ __launch_bounds__(256) void softmax_h(unsigned short* __restrict__ P, int cols) {
    __shared__ float buf[1920];
    __shared__ float red[4];
    size_t row = blockIdx.x;
    unsigned short* p = P + row * (size_t)cols;
    int tid = threadIdx.x;
    int nq = cols >> 2;

    float lmax = -1e30f;
    for (int q = tid; q < nq; q += 256) {
        ushort4 h = ((const ushort4*)p)[q];
        float v0 = h2f(h.x), v1 = h2f(h.y), v2 = h2f(h.z), v3 = h2f(h.w);
        buf[q * 4 + 0] = v0; buf[q * 4 + 1] = v1;
        buf[q * 4 + 2] = v2; buf[q * 4 + 3] = v3;
        lmax = fmaxf(lmax, fmaxf(fmaxf(v0, v1), fmaxf(v2, v3)));
    }
    #pragma unroll
    for (int o = 1; o < 64; o <<= 1) lmax = fmaxf(lmax, __shfl_xor(lmax, o));
    if ((tid & 63) == 0) red[tid >> 6] = lmax;
    __syncthreads();
    float bmax = fmaxf(fmaxf(red[0], red[1]), fmaxf(red[2], red[3]));

    float lsum = 0.f;
    for (int c = tid; c < cols; c += 256) {
        float e = expf(buf[c] - bmax);
        buf[c] = e;
        lsum += e;
    }
    #pragma unroll
    for (int o = 1; o < 64; o <<= 1) lsum += __shfl_xor(lsum, o);
    __syncthreads();
    if ((tid & 63) == 0) red[tid >> 6] = lsum;
    __syncthreads();
    float inv = 1.0f / (red[0] + red[1] + red[2] + red[3]);

    for (int q = tid; q < nq; q += 256) {
        ushort4 h;
        h.x = f2h(buf[q * 4 + 0] * inv);
        h.y = f2h(buf[q * 4 + 1] * inv);
        h.z = f2h(buf[q * 4 + 2] * inv);
        h.w = f2h(buf[q * 4 + 3] * inv);
        ((ushort4*)p)[q] = h;
    }
}

// ---------------- launch ----------------
extern "C" void kernel_launch(void* const* d_in, const int* in_sizes, int n_in,
                              void* d_out, int out_size, void* d_ws, size_t ws_size,
                              hipStream_t stream) {
    (void)in_sizes; (void)n_in; (void)out_size; (void)ws_size;
    const float* x  = (const float*)d_in[0];
    const float* g  = (const float*)d_in[1];
    const float* Wq = (const float*)d_in[2];
    const float* Wg = (const float*)d_in[3];
    float* out = (float*)d_out;

    const size_t GE = (size_t)Mrows * Cdim;      // 7,864,320 elems
    char* ws = (char*)d_ws;
    size_t off = 0;
    auto alloc = [&](size_t bytes) { char* p = ws + off; off += (bytes + 255) & ~(size_t)255; return p; };

    float* meang = (float*)alloc(Bsz * Cdim * 4);
    float* part  = (float*)alloc(Bsz * 40 * Cdim * 4);
    float* invn  = (float*)alloc(Mrows * 4);
    unsigned short* gh   = (unsigned short*)alloc(GE * 2);            // g f16
    unsigned short* gTh  = (unsigned short*)alloc(GE * 2);            // [NBLK][512][192]
    unsigned short* qh   = (unsigned short*)alloc(GE * 2);            // q f16; reused as g2T
    unsigned short* wqh  = (unsigned short*)alloc((size_t)Cdim * Cdim * 2);
    unsigned short* wgh  = (unsigned short*)alloc((size_t)Cdim * Cdim * 2);
    unsigned short* rqh  = (unsigned short*)alloc(GE * 2);
    unsigned short* rgh  = (unsigned short*)alloc(GE * 2);
    unsigned short* g2h  = (unsigned short*)alloc(GE * 2);
    unsigned short* sbh  = (unsigned short*)alloc((size_t)NBLK * BLK * BLK * 2);
    unsigned short* s2h  = (unsigned short*)alloc((size_t)Bsz * Ntok * Ntok * 2);  // 59 MB
    unsigned short* g2Th = qh;                                        // [Bsz][512][1920]

    // 1. token mean; per-row inv norms (f32 sources)
    mean_partial<<<dim3(Bsz, 40), 512, 0, stream>>>(g, part);
    mean_final<<<Bsz, 512, 0, stream>>>(part, meang);
    invnorm_k<<<Mrows / 4, 256, 0, stream>>>(g, invn);

    // 2. f16 conversions
    cvt_k<<<(int)(GE / 4 + 255) / 256, 256, 0, stream>>>(g, nullptr, gh, (int)(GE / 4));
    cvt_k<<<(int)(GE / 4 + 255) / 256, 256, 0, stream>>>(x, meang, qh, (int)(GE / 4));
    cvt_k<<<(Cdim * Cdim / 4) / 256, 256, 0, stream>>>(Wq, nullptr, wqh, Cdim * Cdim / 4);
    cvt_k<<<(Cdim * Cdim / 4) / 256, 256, 0, stream>>>(Wg, nullptr, wgh, Cdim * Cdim / 4);

    // 2b. gT: per 192-block transpose  [NBLK][512][192]
    transpose1<<<dim3(Cdim / 64, BLK / 64, NBLK), 256, 0, stream>>>(
        gh, gTh, BLK, Cdim, (long)BLK * Cdim, (long)Cdim * BLK);

    // 3. rel_q = q @ Wq^T -> f16  [15360,512]  (<2,4> BK64, 960 blocks)
    mfma_gemm<2, 4, 64><<<dim3(Cdim / 128, Mrows / 64), 256, 0, stream>>>(
        qh, wqh, nullptr, rqh, Cdim, Cdim, Cdim, 0, 0, 0, 1.0f, nullptr, nullptr, 0);

    // 4. block scores = (g·g^T)*invn_i*invn_j*SCALE -> f16  [80][192][192]  (720 blocks)
    mfma_gemm<2, 2, 32><<<dim3(3, 3, NBLK), 256, 0, stream>>>(
        gh, gh, nullptr, sbh, BLK, Cdim, Cdim,
        (long)BLK * Cdim, (long)BLK * Cdim, (long)BLK * BLK,
        SCALE, invn, invn, BLK);

    // 5. block softmax in place
    softmax_h<<<NBLK * BLK, 256, 0, stream>>>(sbh, BLK);

    // 6. g2 = attn · (gT)^T -> f16  [80][192][512]  (<2,4> BK64, 960 blocks, K=192)
    mfma_gemm<2, 4, 64><<<dim3(Cdim / 128, BLK / 64, NBLK), 256, 0, stream>>>(
        sbh, gTh, nullptr, g2h, Cdim, BLK, BLK,
        (long)BLK * BLK, (long)Cdim * BLK, (long)BLK * Cdim,
        1.0f, nullptr, nullptr, 0);

    // 6b. g2T: per-batch transpose  [Bsz][512][1920]  (into dead q buffer)
    transpose1<<<dim3(Cdim / 64, Ntok / 64, Bsz), 256, 0, stream>>>(
        g2h, g2Th, Ntok, Cdim, (long)Ntok * Cdim, (long)Cdim * Ntok);

    // 7. rel_g = g2 @ Wg^T -> f16  [15360,512]  (<2,4> BK64, 960 blocks)
    mfma_gemm<2, 4, 64><<<dim3(Cdim / 128, Mrows / 64), 256, 0, stream>>>(
        g2h, wgh, nullptr, rgh, Cdim, Cdim, Cdim, 0, 0, 0, 1.0f, nullptr, nullptr, 0);

    // 8. global scores = rel_q @ rel_g^T * SCALE -> f16  [8][1920][1920]  (<4,4> BK32, 1800 blocks)
    mfma_gemm<4, 4, 32><<<dim3(Ntok / 128, Ntok / 128, Bsz), 256, 0, stream>>>(
        rqh, rgh, nullptr, s2h, Ntok, Cdim, Cdim,
        (long)Ntok * Cdim, (long)Ntok * Cdim, (long)Ntok * Ntok,
        SCALE, nullptr, nullptr, 0);

    // 9. global softmax in place  (15360 rows of 1920)
    softmax_h<<<Bsz * Ntok, 256, 0, stream>>>(s2h, Ntok);

    // 10. out = attn2 · (g2T)^T -> f32  [8][1920][512]  (<2,4> BK64, 960 blocks, K=1920)
    mfma_gemm<2, 4, 64><<<dim3(Cdim / 128, Ntok / 64, Bsz), 256, 0, stream>>>(
        s2h, g2Th, out, nullptr, Cdim, Ntok, Ntok,
        (long)Ntok * Ntok, (long)Cdim * Ntok, (long)Ntok * Cdim,
        1.0f, nullptr, nullptr, 0);
}

// Round 12
// 262.741 us; speedup vs baseline: 1.1713x; 1.0325x over previous
//
#include <hip/hip_runtime.h>
#include <math.h>

// Problem constants
constexpr int Bsz  = 8;
constexpr int Ntok = 1920;
constexpr int Cdim = 512;
constexpr int BLK  = 192;
constexpr int Mrows = Bsz * Ntok;      // 15360
constexpr int NBLK  = Mrows / BLK;     // 80
constexpr float SCALE = 0.02209708691207961f;  // 2048^-0.5

typedef _Float16 half8 __attribute__((ext_vector_type(8)));
typedef float    f32x4 __attribute__((ext_vector_type(4)));

#define GLOAD_LDS16(gp, lp) __builtin_amdgcn_global_load_lds( \
    (const __attribute__((address_space(1))) void*)(gp),      \
    (__attribute__((address_space(3))) void*)(lp), 16, 0, 0)

// ---- f16 helpers ----
__device__ inline unsigned short f2h(float f) {
    _Float16 h = (_Float16)f;
    return __builtin_bit_cast(unsigned short, h);
}
__device__ inline float h2f(unsigned short u) {
    return (float)__builtin_bit_cast(_Float16, u);
}

// slot swizzle (involution, applied to global source chunk AND ds_read chunk)
template<int BK> __device__ inline int smask(int r) {
    return (BK == 32) ? ((r & 3) ^ ((r >> 2) & 3)) : (r & 7);
}

// counted vmcnt wait (T4): leave N loads in flight
template<int N> __device__ __forceinline__ void vm_wait() {
    if constexpr (N == 0)      asm volatile("s_waitcnt vmcnt(0)" ::: "memory");
    else if constexpr (N == 2) asm volatile("s_waitcnt vmcnt(2)" ::: "memory");
    else if constexpr (N == 4) asm volatile("s_waitcnt vmcnt(4)" ::: "memory");
    else if constexpr (N == 6) asm volatile("s_waitcnt vmcnt(6)" ::: "memory");
    else                       asm volatile("s_waitcnt vmcnt(8)" ::: "memory");
}

// ---------------- token mean (two-stage) ----------------
__global__ void mean_partial(const float* __restrict__ g, float* __restrict__ part) {
    int b = blockIdx.x, t = blockIdx.y, c = threadIdx.x;
    const float* p = g + ((size_t)b * Ntok + (size_t)t * 48) * Cdim + c;
    float s = 0.f;
    #pragma unroll 4
    for (int n = 0; n < 48; ++n) s += p[(size_t)n * Cdim];
    part[((size_t)b * 40 + t) * Cdim + c] = s;
}

__global__ void mean_final(const float* __restrict__ part, float* __restrict__ meang) {
    int b = blockIdx.x, c = threadIdx.x;
    float s = 0.f;
    for (int t = 0; t < 40; ++t) s += part[((size_t)b * 40 + t) * Cdim + c];
    meang[b * Cdim + c] = s * (1.0f / (float)Ntok);
}

// ---------------- per-row inverse norm of g (f32 source) ----------------
__global__ void invnorm_k(const float* __restrict__ g, float* __restrict__ invn) {
    int wid = threadIdx.x >> 6, lane = threadIdx.x & 63;
    int row = blockIdx.x * 4 + wid;
    const float* p = g + (size_t)row * Cdim;
    float ss = 0.f;
    #pragma unroll
    for (int i = lane; i < Cdim; i += 64) { float v = p[i]; ss += v * v; }
    #pragma unroll
    for (int o = 1; o < 64; o <<= 1) ss += __shfl_xor(ss, o);
    if (lane == 0) {
        float n = sqrtf(ss);
        invn[row] = 1.0f / fmaxf(n, 1e-12f);
    }
}

// ---------------- f32 -> f16 convert, optional per-token bias ----------------
__global__ void cvt_k(const float* __restrict__ src, const float* __restrict__ bias,
                      unsigned short* __restrict__ dst, int n4) {
    int i = blockIdx.x * 256 + threadIdx.x;
    if (i >= n4) return;
    float4 v = ((const float4*)src)[i];
    if (bias) {
        int b  = i / (Ntok * Cdim / 4);
        int c4 = (i & (Cdim / 4 - 1)) << 2;
        float4 bv = *(const float4*)&bias[b * Cdim + c4];
        v.x += bv.x; v.y += bv.y; v.z += bv.z; v.w += bv.w;
    }
    ushort4 h;
    h.x = f2h(v.x); h.y = f2h(v.y); h.z = f2h(v.z); h.w = f2h(v.w);
    ((ushort4*)dst)[i] = h;
}

// ---------------- batched 64x64-tiled u16 transpose ----------------
__global__ __launch_bounds__(256) void transpose1(
    const unsigned short* __restrict__ in, unsigned short* __restrict__ out,
    int R, int C, long inB, long outB)
{
    int z = blockIdx.z;
    in  += (size_t)z * inB;
    out += (size_t)z * outB;
    __shared__ unsigned short th[64][68];
    int r0 = blockIdx.y * 64, c0 = blockIdx.x * 64;
    int tr = threadIdx.x >> 4, tc = (threadIdx.x & 15) * 4;
    for (int rr = tr; rr < 64; rr += 16) {
        ushort4 h = *(const ushort4*)&in[(size_t)(r0 + rr) * C + c0 + tc];
        th[tc + 0][rr] = h.x; th[tc + 1][rr] = h.y; th[tc + 2][rr] = h.z; th[tc + 3][rr] = h.w;
    }
    __syncthreads();
    for (int cc = tr; cc < 64; cc += 16) {
        ushort4 h = *(const ushort4*)&th[cc][tc];
        *(ushort4*)&out[(size_t)(c0 + cc) * R + r0 + tc] = h;
    }
}

// ---------------- f16 MFMA GEMM (NT), depth-2 counted-vmcnt pipeline ------------
// (unchanged from R11 -- used for all GEMMs except the global score GEMM)
template<int FM, int FN, int BK>
__global__ __launch_bounds__(256) void mfma_gemm(
    const unsigned short* __restrict__ A, const unsigned short* __restrict__ B,
    float* __restrict__ Of32, unsigned short* __restrict__ Oh,
    int N, int K, int ld,
    long aB, long bB, long oB,
    float alpha, const float* __restrict__ rs, const float* __restrict__ cs, int sB)
{
    constexpr int BM = FM * 32, BN = FN * 32;
    constexpr int RPC = 512 / BK;
    constexpr int LPR = BK / 8;
    constexpr int NCH = (BM + BN) / RPC;
    constexpr int CPW = NCH / 4;
    int z = blockIdx.z;

    int gx = gridDim.x;
    int nwg = gx * gridDim.y;
    int orig = blockIdx.y * gx + blockIdx.x;
    int q = nwg >> 3, r = nwg & 7;
    int xcd = orig & 7, idx = orig >> 3;
    int wgid = (xcd < r ? xcd * (q + 1) : r * (q + 1) + (xcd - r) * q) + idx;
    int m0 = (wgid / gx) * BM, n0 = (wgid % gx) * BN;

    __shared__ __align__(16) unsigned short As[2][BM * BK];
    __shared__ __align__(16) unsigned short Bs[2][BN * BK];

    int tid  = threadIdx.x;
    int lane = tid & 63, wid = tid >> 6;
    int wm = (wid >> 1) * (FM * 16), wn = (wid & 1) * (FN * 16);

    int srow = lane / LPR;
    int sgc  = (lane % LPR) ^ smask<BK>(srow);

    const unsigned short* csrc[CPW];
    unsigned short* cdst0[CPW];
    unsigned short* cdst1[CPW];
    #pragma unroll
    for (int i = 0; i < CPW; ++i) {
        int c = wid * CPW + i;
        if (c < BM / RPC) {
            csrc[i]  = A + (size_t)z * aB + (size_t)(m0 + c * RPC + srow) * ld + sgc * 8;
            cdst0[i] = &As[0][c * 512];
            cdst1[i] = &As[1][c * 512];
        } else {
            int cb = c - BM / RPC;
            csrc[i]  = B + (size_t)z * bB + (size_t)(n0 + cb * RPC + srow) * ld + sgc * 8;
            cdst0[i] = &Bs[0][cb * 512];
            cdst1[i] = &Bs[1][cb * 512];
        }
    }

    f32x4 acc[FM][FN] = {};
    int fr = lane & 15, kq = lane >> 4;

    const int nt = K / BK;
    #pragma unroll
    for (int i = 0; i < CPW; ++i) GLOAD_LDS16(csrc[i], cdst0[i]);
    #pragma unroll
    for (int i = 0; i < CPW; ++i) GLOAD_LDS16(csrc[i] + BK, cdst1[i]);

    for (int t = 0; t < nt; ++t) {
        int cur = t & 1;
        if (t + 1 < nt) vm_wait<CPW>(); else vm_wait<0>();
        __builtin_amdgcn_sched_barrier(0);
        __builtin_amdgcn_s_barrier();
        __builtin_amdgcn_sched_barrier(0);

        const unsigned short* Ab = As[cur];
        const unsigned short* Bb = Bs[cur];
        #pragma unroll
        for (int ks = 0; ks < BK / 32; ++ks) {
            int slot = ks * 4 + kq;
            half8 a[FM], b[FN];
            #pragma unroll
            for (int f = 0; f < FM; ++f) {
                int rr = wm + f * 16 + fr;
                a[f] = *(const half8*)&Ab[rr * BK + ((slot ^ smask<BK>(rr)) << 3)];
            }
            #pragma unroll
            for (int f = 0; f < FN; ++f) {
                int rr = wn + f * 16 + fr;
                b[f] = *(const half8*)&Bb[rr * BK + ((slot ^ smask<BK>(rr)) << 3)];
            }
            #pragma unroll
            for (int i = 0; i < FM; ++i)
                #pragma unroll
                for (int j = 0; j < FN; ++j)
                    acc[i][j] = __builtin_amdgcn_mfma_f32_16x16x32_f16(a[i], b[j], acc[i][j], 0, 0, 0);
        }

        __builtin_amdgcn_sched_barrier(0);
        __builtin_amdgcn_s_barrier();
        if (t + 2 < nt) {
            const int k2 = (t + 2) * BK;
            #pragma unroll
            for (int i = 0; i < CPW; ++i)
                GLOAD_LDS16(csrc[i] + k2, cur ? cdst1[i] : cdst0[i]);
        }
    }

    float* O          = Of32 ? Of32 + (size_t)z * oB : nullptr;
    unsigned short* H = Oh   ? Oh   + (size_t)z * oB : nullptr;
    int fq = lane >> 4;
    #pragma unroll
    for (int i = 0; i < FM; ++i) {
        #pragma unroll
        for (int r4 = 0; r4 < 4; ++r4) {
            int gm = m0 + wm + i * 16 + fq * 4 + r4;
            float rf = alpha * (rs ? rs[(size_t)z * sB + gm] : 1.0f);
            #pragma unroll
            for (int j = 0; j < FN; ++j) {
                int gn = n0 + wn + j * 16 + fr;
                float v = acc[i][j][r4] * rf * (cs ? cs[(size_t)z * sB + gn] : 1.0f);
                size_t off = (size_t)gm * N + gn;
                if (O) O[off] = v;
                else   H[off] = f2h(v);
            }
        }
    }
}

// ---------------- 256x256-tile 8-wave f16 GEMM (NT) for the global score --------
// O_h = alpha * (A · B^T), A [M,ld], B [N,ld] k-contiguous f16, f32 accum.
// 512 threads = 8 waves (2M x 4N), wave tile 128x64 (42.7 FLOP per LDS byte).
// BK=64, LDS 2x64KB dbuf, depth-2 counted-vmcnt (leave next tile's 8 loads
// in flight across the barrier). Clamped loads / guarded stores for M,N=1920.
__global__ __launch_bounds__(512, 2) void gemm256(
    const unsigned short* __restrict__ A, const unsigned short* __restrict__ B,
    unsigned short* __restrict__ Oh,
    int M, int N, int K, int ld,
    long aB, long bB, long oB, float alpha)
{
    int z = blockIdx.z;
    int gx = gridDim.x;
    int nwg = gx * gridDim.y;
    int orig = blockIdx.y * gx + blockIdx.x;
    int q = nwg >> 3, r = nwg & 7;
    int xcd = orig & 7, idx = orig >> 3;
    int wgid = (xcd < r ? xcd * (q + 1) : r * (q + 1) + (xcd - r) * q) + idx;
    int m0 = (wgid / gx) * 256, n0 = (wgid % gx) * 256;

    __shared__ __align__(16) unsigned short As[2][256 * 64];   // 64 KB
    __shared__ __align__(16) unsigned short Bs[2][256 * 64];   // 64 KB

    int tid = threadIdx.x, lane = tid & 63, wid = tid >> 6;
    int wr = wid >> 2, wc = wid & 3;       // wave tile: rows wr*128, cols wc*64
    const unsigned short* Az = A + (size_t)z * aB;
    const unsigned short* Bz = B + (size_t)z * bB;

    // staging: 64 chunks of 1KB (32 A + 32 B), wave owns 4+4; lane -> row l>>3,
    // pre-swizzled slot (l&7)^(l>>3) so linear LDS + swizzled read match.
    int srow8 = lane >> 3;
    int sslot = (lane & 7) ^ srow8;

    auto stageT = [&](int t) {
        int cur = t & 1;
        const int koff = t * 64;
        #pragma unroll
        for (int i = 0; i < 4; ++i) {
            int c = wid * 4 + i;               // 0..31
            int rrow = c * 8 + srow8;          // 0..255
            int gr = min(m0 + rrow, M - 1);
            GLOAD_LDS16(Az + (size_t)gr * ld + koff + sslot * 8, &As[cur][c * 512]);
        }
        #pragma unroll
        for (int i = 0; i < 4; ++i) {
            int c = wid * 4 + i;
            int rrow = c * 8 + srow8;
            int gc = min(n0 + rrow, N - 1);
            GLOAD_LDS16(Bz + (size_t)gc * ld + koff + sslot * 8, &Bs[cur][c * 512]);
        }
    };

    f32x4 acc[8][4] = {};
    int fr = lane & 15, kq = lane >> 4;

    const int nt = K / 64;                     // assumes nt >= 2 (K=512 -> 8)
    stageT(0);
    stageT(1);

    for (int t = 0; t < nt; ++t) {
        int cur = t & 1;
        if (t + 1 < nt) vm_wait<8>(); else vm_wait<0>();
        __builtin_amdgcn_sched_barrier(0);
        __builtin_amdgcn_s_barrier();
        __builtin_amdgcn_sched_barrier(0);

        const unsigned short* Ab = As[cur];
        const unsigned short* Bb = Bs[cur];
        __builtin_amdgcn_s_setprio(1);
        #pragma unroll
        for (int mh = 0; mh < 2; ++mh) {
            #pragma unroll
            for (int nh = 0; nh < 2; ++nh) {
                half8 a[4][2], b[2][2];
                #pragma unroll
                for (int mf = 0; mf < 4; ++mf) {
                    int rr = wr * 128 + mh * 64 + mf * 16 + fr;
                    #pragma unroll
                    for (int ks = 0; ks < 2; ++ks) {
                        int slot = (ks * 4 + kq) ^ (rr & 7);
                        a[mf][ks] = *(const half8*)&Ab[rr * 64 + slot * 8];
                    }
                }
                #pragma unroll
                for (int nf = 0; nf < 2; ++nf) {
                    int rr = wc * 64 + nh * 32 + nf * 16 + fr;
                    #pragma unroll
                    for (int ks = 0; ks < 2; ++ks) {
                        int slot = (ks * 4 + kq) ^ (rr & 7);
                        b[nf][ks] = *(const half8*)&Bb[rr * 64 + slot * 8];
                    }
                }
                #pragma unroll
                for (int mf = 0; mf < 4; ++mf)
                    #pragma unroll
                    for (int nf = 0; nf < 2; ++nf)
                        #pragma unroll
                        for (int ks = 0; ks < 2; ++ks)
                            acc[mh * 4 + mf][nh * 2 + nf] =
                                __builtin_amdgcn_mfma_f32_16x16x32_f16(
                                    a[mf][ks], b[nf][ks], acc[mh * 4 + mf][nh * 2 + nf], 0, 0, 0);
            }
        }
        __builtin_amdgcn_s_setprio(0);

        __builtin_amdgcn_sched_barrier(0);
        __builtin_amdgcn_s_barrier();
        __builtin_amdgcn_sched_barrier(0);
        if (t + 2 < nt) stageT(t + 2);
    }

    unsigned short* H = Oh + (size_t)z * oB;
    int fq = lane >> 4;
    #pragma unroll
    for (int mi = 0; mi < 8; ++mi) {
        #pragma unroll
        for (int r4 = 0; r4 < 4; ++r4) {
            int gm = m0 + wr * 128 + mi * 16 + fq * 4 + r4;
            if (gm >= M) continue;
            #pragma unroll
            for (int ni = 0; ni < 4; ++ni) {
                int gn = n0 + wc * 64 + ni * 16 + fr;
                if (gn >= N) continue;
                H[(size_t)gm * N + gn] = f2h(acc[mi][ni][r4] * alpha);
            }
        }
    }
}

// ---------------- in-place row softmax on f16 scores ----------------
__global__ __launch_bounds__(256) void softmax_h(unsigned short* __restrict__ P, int cols) {
    __shared__ float buf[1920];
    __shared__ float red[4];
    size_t row = blockIdx.x;
    unsigned short* p = P + row * (size_t)cols;
    int tid = threadIdx.x;
    int nq = cols >> 2;

    float lmax = -1e30f;
    for (int q = tid; q < nq; q += 256) {
        ushort4 h = ((const ushort4*)p)[q];
        float v0 = h2f(h.x), v1 = h2f(h.y), v2 = h2f(h.z), v3 = h2f(h.w);
        buf[q * 4 + 0] = v0; buf[q * 4 + 1] = v1;
        buf[q * 4 + 2] = v2; buf[q * 4 + 3] = v3;
        lmax = fmaxf(lmax, fmaxf(fmaxf(v0, v1), fmaxf(v2, v3)));
    }
    #pragma unroll
    for (int o = 1; o < 64; o <<= 1) lmax = fmaxf(lmax, __shfl_xor(lmax, o));
    if ((tid & 63) == 0) red[tid >> 6] = lmax;
    __syncthreads();
    float bmax = fmaxf(fmaxf(red[0], red[1]), fmaxf(red[2], red[3]));

    float lsum = 0.f;
    for (int c = tid; c < cols; c += 256) {
        float e = expf(buf[c] - bmax);
        buf[c] = e;
        lsum += e;
    }
    #pragma unroll
    for (int o = 1; o < 64; o <<= 1) lsum += __shfl_xor(lsum, o);
    __syncthreads();
    if ((tid & 63) == 0) red[tid >> 6] = lsum;
    __syncthreads();
    float inv = 1.0f / (red[0] + red[1] + red[2] + red[3]);

    for (int q = tid; q < nq; q += 256) {
        ushort4 h;
        h.x = f2h(buf[q * 4 + 0] * inv);
        h.y = f2h(buf[q * 4 + 1] * inv);
        h.z = f2h(buf[q * 4 + 2] * inv);
        h.w = f2h(buf[q * 4 + 3] * inv);
        ((ushort4*)p)[q] = h;
    }
}

// ---------------- launch ----------------
extern "C" void kernel_launch(void* const* d_in, const int* in_sizes, int n_in,
                              void* d_out, int out_size, void* d_ws, size_t ws_size,
                              hipStream_t stream) {
    (void)in_sizes; (void)n_in; (void)out_size; (void)ws_size;
    const float* x  = (const float*)d_in[0];
    const float* g  = (const float*)d_in[1];
    const float* Wq = (const float*)d_in[2];
    const float* Wg = (const float*)d_in[3];
    float* out = (float*)d_out;

    const size_t GE = (size_t)Mrows * Cdim;      // 7,864,320 elems
    char* ws = (char*)d_ws;
    size_t off = 0;
    auto alloc = [&](size_t bytes) { char* p = ws + off; off += (bytes + 255) & ~(size_t)255; return p; };

    float* meang = (float*)alloc(Bsz * Cdim * 4);
    float* part  = (float*)alloc(Bsz * 40 * Cdim * 4);
    float* invn  = (float*)alloc(Mrows * 4);
    unsigned short* gh   = (unsigned short*)alloc(GE * 2);            // g f16
    unsigned short* gTh  = (unsigned short*)alloc(GE * 2);            // [NBLK][512][192]
    unsigned short* qh   = (unsigned short*)alloc(GE * 2);            // q f16; reused as g2T
    unsigned short* wqh  = (unsigned short*)alloc((size_t)Cdim * Cdim * 2);
    unsigned short* wgh  = (unsigned short*)alloc((size_t)Cdim * Cdim * 2);
    unsigned short* rqh  = (unsigned short*)alloc(GE * 2);
    unsigned short* rgh  = (unsigned short*)alloc(GE * 2);
    unsigned short* g2h  = (unsigned short*)alloc(GE * 2);
    unsigned short* sbh  = (unsigned short*)alloc((size_t)NBLK * BLK * BLK * 2);
    unsigned short* s2h  = (unsigned short*)alloc((size_t)Bsz * Ntok * Ntok * 2);  // 59 MB
    unsigned short* g2Th = qh;                                        // [Bsz][512][1920]

    // 1. token mean; per-row inv norms (f32 sources)
    mean_partial<<<dim3(Bsz, 40), 512, 0, stream>>>(g, part);
    mean_final<<<Bsz, 512, 0, stream>>>(part, meang);
    invnorm_k<<<Mrows / 4, 256, 0, stream>>>(g, invn);

    // 2. f16 conversions
    cvt_k<<<(int)(GE / 4 + 255) / 256, 256, 0, stream>>>(g, nullptr, gh, (int)(GE / 4));
    cvt_k<<<(int)(GE / 4 + 255) / 256, 256, 0, stream>>>(x, meang, qh, (int)(GE / 4));
    cvt_k<<<(Cdim * Cdim / 4) / 256, 256, 0, stream>>>(Wq, nullptr, wqh, Cdim * Cdim / 4);
    cvt_k<<<(Cdim * Cdim / 4) / 256, 256, 0, stream>>>(Wg, nullptr, wgh, Cdim * Cdim / 4);

    // 2b. gT: per 192-block transpose  [NBLK][512][192]
    transpose1<<<dim3(Cdim / 64, BLK / 64, NBLK), 256, 0, stream>>>(
        gh, gTh, BLK, Cdim, (long)BLK * Cdim, (long)Cdim * BLK);

    // 3. rel_q = q @ Wq^T -> f16  [15360,512]  (<2,4> BK64, 960 blocks)
    mfma_gemm<2, 4, 64><<<dim3(Cdim / 128, Mrows / 64), 256, 0, stream>>>(
        qh, wqh, nullptr, rqh, Cdim, Cdim, Cdim, 0, 0, 0, 1.0f, nullptr, nullptr, 0);

    // 4. block scores = (g·g^T)*invn_i*invn_j*SCALE -> f16  [80][192][192]  (720 blocks)
    mfma_gemm<2, 2, 32><<<dim3(3, 3, NBLK), 256, 0, stream>>>(
        gh, gh, nullptr, sbh, BLK, Cdim, Cdim,
        (long)BLK * Cdim, (long)BLK * Cdim, (long)BLK * BLK,
        SCALE, invn, invn, BLK);

    // 5. block softmax in place
    softmax_h<<<NBLK * BLK, 256, 0, stream>>>(sbh, BLK);

    // 6. g2 = attn · (gT)^T -> f16  [80][192][512]  (<2,4> BK64, 960 blocks, K=192)
    mfma_gemm<2, 4, 64><<<dim3(Cdim / 128, BLK / 64, NBLK), 256, 0, stream>>>(
        sbh, gTh, nullptr, g2h, Cdim, BLK, BLK,
        (long)BLK * BLK, (long)Cdim * BLK, (long)BLK * Cdim,
        1.0f, nullptr, nullptr, 0);

    // 6b. g2T: per-batch transpose  [Bsz][512][1920]  (into dead q buffer)
    transpose1<<<dim3(Cdim / 64, Ntok / 64, Bsz), 256, 0, stream>>>(
        g2h, g2Th, Ntok, Cdim, (long)Ntok * Cdim, (long)Cdim * Ntok);

    // 7. rel_g = g2 @ Wg^T -> f16  [15360,512]  (<2,4> BK64, 960 blocks)
    mfma_gemm<2, 4, 64><<<dim3(Cdim / 128, Mrows / 64), 256, 0, stream>>>(
        g2h, wgh, nullptr, rgh, Cdim, Cdim, Cdim, 0, 0, 0, 1.0f, nullptr, nullptr, 0);

    // 8. global scores = rel_q @ rel_g^T * SCALE -> f16  [8][1920][1920]
    //    256^2 8-wave kernel: 8x8 tiles (clamped to 1920) x 8 batches = 512 blocks
    gemm256<<<dim3(8, 8, Bsz), 512, 0, stream>>>(
        rqh, rgh, s2h, Ntok, Ntok, Cdim, Cdim,
        (long)Ntok * Cdim, (long)Ntok * Cdim, (long)Ntok * Ntok, SCALE);

    // 9. global softmax in place  (15360 rows of 1920)
    softmax_h<<<Bsz * Ntok, 256, 0, stream>>>(s2h, Ntok);

    // 10. out = attn2 · (g2T)^T -> f32  [8][1920][512]  (<2,4> BK64, 960 blocks, K=1920)
    mfma_gemm<2, 4, 64><<<dim3(Cdim / 128, Ntok / 64, Bsz), 256, 0, stream>>>(
        s2h, g2Th, out, nullptr, Cdim, Ntok, Ntok,
        (long)Ntok * Ntok, (long)Cdim * Ntok, (long)Ntok * Cdim,
        1.0f, nullptr, nullptr, 0);
}

// Round 13
// 261.112 us; speedup vs baseline: 1.1786x; 1.0062x over previous
//
#include <hip/hip_runtime.h>
#include <math.h>

// Problem constants
constexpr int Bsz  = 8;
constexpr int Ntok = 1920;
constexpr int Cdim = 512;
constexpr int BLK  = 192;
constexpr int Mrows = Bsz * Ntok;      // 15360
constexpr int NBLK  = Mrows / BLK;     // 80
constexpr float SCALE = 0.02209708691207961f;  // 2048^-0.5

typedef _Float16 half8 __attribute__((ext_vector_type(8)));
typedef float    f32x4 __attribute__((ext_vector_type(4)));

#define GLOAD_LDS16(gp, lp) __builtin_amdgcn_global_load_lds( \
    (const __attribute__((address_space(1))) void*)(gp),      \
    (__attribute__((address_space(3))) void*)(lp), 16, 0, 0)

// ---- f16 helpers ----
__device__ inline unsigned short f2h(float f) {
    _Float16 h = (_Float16)f;
    return __builtin_bit_cast(unsigned short, h);
}
__device__ inline float h2f(unsigned short u) {
    return (float)__builtin_bit_cast(_Float16, u);
}

// slot swizzle (involution, applied to global source chunk AND ds_read chunk)
template<int BK> __device__ inline int smask(int r) {
    return (BK == 32) ? ((r & 3) ^ ((r >> 2) & 3)) : (r & 7);
}

// counted vmcnt wait (T4): leave N loads in flight
template<int N> __device__ __forceinline__ void vm_wait() {
    if constexpr (N == 0)      asm volatile("s_waitcnt vmcnt(0)" ::: "memory");
    else if constexpr (N == 2) asm volatile("s_waitcnt vmcnt(2)" ::: "memory");
    else if constexpr (N == 4) asm volatile("s_waitcnt vmcnt(4)" ::: "memory");
    else if constexpr (N == 6) asm volatile("s_waitcnt vmcnt(6)" ::: "memory");
    else                       asm volatile("s_waitcnt vmcnt(8)" ::: "memory");
}

// ---------------- token mean (two-stage) ----------------
__global__ void mean_partial(const float* __restrict__ g, float* __restrict__ part) {
    int b = blockIdx.x, t = blockIdx.y, c = threadIdx.x;
    const float* p = g + ((size_t)b * Ntok + (size_t)t * 48) * Cdim + c;
    float s = 0.f;
    #pragma unroll 4
    for (int n = 0; n < 48; ++n) s += p[(size_t)n * Cdim];
    part[((size_t)b * 40 + t) * Cdim + c] = s;
}

__global__ void mean_final(const float* __restrict__ part, float* __restrict__ meang) {
    int b = blockIdx.x, c = threadIdx.x;
    float s = 0.f;
    for (int t = 0; t < 40; ++t) s += part[((size_t)b * 40 + t) * Cdim + c];
    meang[b * Cdim + c] = s * (1.0f / (float)Ntok);
}

// ---------------- per-row inverse norm of g (f32 source) ----------------
__global__ void invnorm_k(const float* __restrict__ g, float* __restrict__ invn) {
    int wid = threadIdx.x >> 6, lane = threadIdx.x & 63;
    int row = blockIdx.x * 4 + wid;
    const float* p = g + (size_t)row * Cdim;
    float ss = 0.f;
    #pragma unroll
    for (int i = lane; i < Cdim; i += 64) { float v = p[i]; ss += v * v; }
    #pragma unroll
    for (int o = 1; o < 64; o <<= 1) ss += __shfl_xor(ss, o);
    if (lane == 0) {
        float n = sqrtf(ss);
        invn[row] = 1.0f / fmaxf(n, 1e-12f);
    }
}

// ---------------- f32 -> f16 convert, optional per-token bias ----------------
__global__ void cvt_k(const float* __restrict__ src, const float* __restrict__ bias,
                      unsigned short* __restrict__ dst, int n4) {
    int i = blockIdx.x * 256 + threadIdx.x;
    if (i >= n4) return;
    float4 v = ((const float4*)src)[i];
    if (bias) {
        int b  = i / (Ntok * Cdim / 4);
        int c4 = (i & (Cdim / 4 - 1)) << 2;
        float4 bv = *(const float4*)&bias[b * Cdim + c4];
        v.x += bv.x; v.y += bv.y; v.z += bv.z; v.w += bv.w;
    }
    ushort4 h;
    h.x = f2h(v.x); h.y = f2h(v.y); h.z = f2h(v.z); h.w = f2h(v.w);
    ((ushort4*)dst)[i] = h;
}

// ---------------- batched 64x64-tiled u16 transpose ----------------
__global__ __launch_bounds__(256) void transpose1(
    const unsigned short* __restrict__ in, unsigned short* __restrict__ out,
    int R, int C, long inB, long outB)
{
    int z = blockIdx.z;
    in  += (size_t)z * inB;
    out += (size_t)z * outB;
    __shared__ unsigned short th[64][68];
    int r0 = blockIdx.y * 64, c0 = blockIdx.x * 64;
    int tr = threadIdx.x >> 4, tc = (threadIdx.x & 15) * 4;
    for (int rr = tr; rr < 64; rr += 16) {
        ushort4 h = *(const ushort4*)&in[(size_t)(r0 + rr) * C + c0 + tc];
        th[tc + 0][rr] = h.x; th[tc + 1][rr] = h.y; th[tc + 2][rr] = h.z; th[tc + 3][rr] = h.w;
    }
    __syncthreads();
    for (int cc = tr; cc < 64; cc += 16) {
        ushort4 h = *(const ushort4*)&th[cc][tc];
        *(ushort4*)&out[(size_t)(c0 + cc) * R + r0 + tc] = h;
    }
}

// ---------------- f16 MFMA GEMM (NT), depth-2 counted-vmcnt pipeline ------------
template<int FM, int FN, int BK>
__global__ __launch_bounds__(256) void mfma_gemm(
    const unsigned short* __restrict__ A, const unsigned short* __restrict__ B,
    float* __restrict__ Of32, unsigned short* __restrict__ Oh,
    int N, int K, int ld,
    long aB, long bB, long oB,
    float alpha, const float* __restrict__ rs, const float* __restrict__ cs, int sB)
{
    constexpr int BM = FM * 32, BN = FN * 32;
    constexpr int RPC = 512 / BK;
    constexpr int LPR = BK / 8;
    constexpr int NCH = (BM + BN) / RPC;
    constexpr int CPW = NCH / 4;
    int z = blockIdx.z;

    int gx = gridDim.x;
    int nwg = gx * gridDim.y;
    int orig = blockIdx.y * gx + blockIdx.x;
    int q = nwg >> 3, r = nwg & 7;
    int xcd = orig & 7, idx = orig >> 3;
    int wgid = (xcd < r ? xcd * (q + 1) : r * (q + 1) + (xcd - r) * q) + idx;
    int m0 = (wgid / gx) * BM, n0 = (wgid % gx) * BN;

    __shared__ __align__(16) unsigned short As[2][BM * BK];
    __shared__ __align__(16) unsigned short Bs[2][BN * BK];

    int tid  = threadIdx.x;
    int lane = tid & 63, wid = tid >> 6;
    int wm = (wid >> 1) * (FM * 16), wn = (wid & 1) * (FN * 16);

    int srow = lane / LPR;
    int sgc  = (lane % LPR) ^ smask<BK>(srow);

    const unsigned short* csrc[CPW];
    unsigned short* cdst0[CPW];
    unsigned short* cdst1[CPW];
    #pragma unroll
    for (int i = 0; i < CPW; ++i) {
        int c = wid * CPW + i;
        if (c < BM / RPC) {
            csrc[i]  = A + (size_t)z * aB + (size_t)(m0 + c * RPC + srow) * ld + sgc * 8;
            cdst0[i] = &As[0][c * 512];
            cdst1[i] = &As[1][c * 512];
        } else {
            int cb = c - BM / RPC;
            csrc[i]  = B + (size_t)z * bB + (size_t)(n0 + cb * RPC + srow) * ld + sgc * 8;
            cdst0[i] = &Bs[0][cb * 512];
            cdst1[i] = &Bs[1][cb * 512];
        }
    }

    f32x4 acc[FM][FN] = {};
    int fr = lane & 15, kq = lane >> 4;

    const int nt = K / BK;
    #pragma unroll
    for (int i = 0; i < CPW; ++i) GLOAD_LDS16(csrc[i], cdst0[i]);
    #pragma unroll
    for (int i = 0; i < CPW; ++i) GLOAD_LDS16(csrc[i] + BK, cdst1[i]);

    for (int t = 0; t < nt; ++t) {
        int cur = t & 1;
        if (t + 1 < nt) vm_wait<CPW>(); else vm_wait<0>();
        __builtin_amdgcn_sched_barrier(0);
        __builtin_amdgcn_s_barrier();
        __builtin_amdgcn_sched_barrier(0);

        const unsigned short* Ab = As[cur];
        const unsigned short* Bb = Bs[cur];
        #pragma unroll
        for (int ks = 0; ks < BK / 32; ++ks) {
            int slot = ks * 4 + kq;
            half8 a[FM], b[FN];
            #pragma unroll
            for (int f = 0; f < FM; ++f) {
                int rr = wm + f * 16 + fr;
                a[f] = *(const half8*)&Ab[rr * BK + ((slot ^ smask<BK>(rr)) << 3)];
            }
            #pragma unroll
            for (int f = 0; f < FN; ++f) {
                int rr = wn + f * 16 + fr;
                b[f] = *(const half8*)&Bb[rr * BK + ((slot ^ smask<BK>(rr)) << 3)];
            }
            #pragma unroll
            for (int i = 0; i < FM; ++i)
                #pragma unroll
                for (int j = 0; j < FN; ++j)
                    acc[i][j] = __builtin_amdgcn_mfma_f32_16x16x32_f16(a[i], b[j], acc[i][j], 0, 0, 0);
        }

        __builtin_amdgcn_sched_barrier(0);
        __builtin_amdgcn_s_barrier();
        if (t + 2 < nt) {
            const int k2 = (t + 2) * BK;
            #pragma unroll
            for (int i = 0; i < CPW; ++i)
                GLOAD_LDS16(csrc[i] + k2, cur ? cdst1[i] : cdst0[i]);
        }
    }

    float* O          = Of32 ? Of32 + (size_t)z * oB : nullptr;
    unsigned short* H = Oh   ? Oh   + (size_t)z * oB : nullptr;
    int fq = lane >> 4;
    #pragma unroll
    for (int i = 0; i < FM; ++i) {
        #pragma unroll
        for (int r4 = 0; r4 < 4; ++r4) {
            int gm = m0 + wm + i * 16 + fq * 4 + r4;
            float rf = alpha * (rs ? rs[(size_t)z * sB + gm] : 1.0f);
            #pragma unroll
            for (int j = 0; j < FN; ++j) {
                int gn = n0 + wn + j * 16 + fr;
                float v = acc[i][j][r4] * rf * (cs ? cs[(size_t)z * sB + gn] : 1.0f);
                size_t off = (size_t)gm * N + gn;
                if (O) O[off] = v;
                else   H[off] = f2h(v);
            }
        }
    }
}

// ---------------- 256x256-tile 8-wave f16 GEMM (NT) for the global score --------
// Same sync skeleton as R12 (proven race-free, 0 bank conflicts). Compute
// restructured for LDS economy: all 8 B-frags cached per K-tile, A streamed
// per m-frag -> 24 ds_read_b128 / wave / K-tile (was 48), MFMA:ds = 2.67.
__global__ __launch_bounds__(512, 2) void gemm256(
    const unsigned short* __restrict__ A, const unsigned short* __restrict__ B,
    unsigned short* __restrict__ Oh,
    int M, int N, int K, int ld,
    long aB, long bB, long oB, float alpha)
{
    int z = blockIdx.z;
    int gx = gridDim.x;
    int nwg = gx * gridDim.y;
    int orig = blockIdx.y * gx + blockIdx.x;
    int q = nwg >> 3, r = nwg & 7;
    int xcd = orig & 7, idx = orig >> 3;
    int wgid = (xcd < r ? xcd * (q + 1) : r * (q + 1) + (xcd - r) * q) + idx;
    int m0 = (wgid / gx) * 256, n0 = (wgid % gx) * 256;

    __shared__ __align__(16) unsigned short As[2][256 * 64];   // 64 KB
    __shared__ __align__(16) unsigned short Bs[2][256 * 64];   // 64 KB

    int tid = threadIdx.x, lane = tid & 63, wid = tid >> 6;
    int wr = wid >> 2, wc = wid & 3;       // wave tile: rows wr*128, cols wc*64
    const unsigned short* Az = A + (size_t)z * aB;
    const unsigned short* Bz = B + (size_t)z * bB;

    int srow8 = lane >> 3;
    int sslot = (lane & 7) ^ srow8;

    auto stageT = [&](int t) {
        int cur = t & 1;
        const int koff = t * 64;
        #pragma unroll
        for (int i = 0; i < 4; ++i) {
            int c = wid * 4 + i;               // 0..31
            int rrow = c * 8 + srow8;          // 0..255
            int gr = min(m0 + rrow, M - 1);
            GLOAD_LDS16(Az + (size_t)gr * ld + koff + sslot * 8, &As[cur][c * 512]);
        }
        #pragma unroll
        for (int i = 0; i < 4; ++i) {
            int c = wid * 4 + i;
            int rrow = c * 8 + srow8;
            int gc = min(n0 + rrow, N - 1);
            GLOAD_LDS16(Bz + (size_t)gc * ld + koff + sslot * 8, &Bs[cur][c * 512]);
        }
    };

    f32x4 acc[8][4] = {};
    int fr = lane & 15, kq = lane >> 4;

    const int nt = K / 64;                     // K=512 -> 8
    stageT(0);
    stageT(1);

    for (int t = 0; t < nt; ++t) {
        int cur = t & 1;
        if (t + 1 < nt) vm_wait<8>(); else vm_wait<0>();
        __builtin_amdgcn_sched_barrier(0);
        __builtin_amdgcn_s_barrier();
        __builtin_amdgcn_sched_barrier(0);

        const unsigned short* Ab = As[cur];
        const unsigned short* Bb = Bs[cur];
        __builtin_amdgcn_s_setprio(1);
        // cache all B fragments for this K-tile (8 x b128 = 32 VGPR)
        half8 b[4][2];
        #pragma unroll
        for (int nf = 0; nf < 4; ++nf) {
            int rr = wc * 64 + nf * 16 + fr;
            #pragma unroll
            for (int ks = 0; ks < 2; ++ks) {
                int slot = (ks * 4 + kq) ^ (rr & 7);
                b[nf][ks] = *(const half8*)&Bb[rr * 64 + slot * 8];
            }
        }
        // stream A per m-frag: 2 reads -> 8 MFMA
        #pragma unroll
        for (int mf = 0; mf < 8; ++mf) {
            int rr = wr * 128 + mf * 16 + fr;
            half8 a[2];
            #pragma unroll
            for (int ks = 0; ks < 2; ++ks) {
                int slot = (ks * 4 + kq) ^ (rr & 7);
                a[ks] = *(const half8*)&Ab[rr * 64 + slot * 8];
            }
            #pragma unroll
            for (int nf = 0; nf < 4; ++nf)
                #pragma unroll
                for (int ks = 0; ks < 2; ++ks)
                    acc[mf][nf] = __builtin_amdgcn_mfma_f32_16x16x32_f16(
                        a[ks], b[nf][ks], acc[mf][nf], 0, 0, 0);
        }
        __builtin_amdgcn_s_setprio(0);

        __builtin_amdgcn_sched_barrier(0);
        __builtin_amdgcn_s_barrier();
        __builtin_amdgcn_sched_barrier(0);
        if (t + 2 < nt) stageT(t + 2);
    }

    unsigned short* H = Oh + (size_t)z * oB;
    int fq = lane >> 4;
    #pragma unroll
    for (int mi = 0; mi < 8; ++mi) {
        #pragma unroll
        for (int r4 = 0; r4 < 4; ++r4) {
            int gm = m0 + wr * 128 + mi * 16 + fq * 4 + r4;
            if (gm >= M) continue;
            #pragma unroll
            for (int ni = 0; ni < 4; ++ni) {
                int gn = n0 + wc * 64 + ni * 16 + fr;
                if (gn >= N) continue;
                H[(size_t)gm * N + gn] = f2h(acc[mi][ni][r4] * alpha);
            }
        }
    }
}

// ---------------- in-place row softmax on f16 scores ----------------
__global__ __launch_bounds__(256) void softmax_h(unsigned short* __restrict__ P, int cols) {
    __shared__ float buf[1920];
    __shared__ float red[4];
    size_t row = blockIdx.x;
    unsigned short* p = P + row * (size_t)cols;
    int tid = threadIdx.x;
    int nq = cols >> 2;

    float lmax = -1e30f;
    for (int q = tid; q < nq; q += 256) {
        ushort4 h = ((const ushort4*)p)[q];
        float v0 = h2f(h.x), v1 = h2f(h.y), v2 = h2f(h.z), v3 = h2f(h.w);
        buf[q * 4 + 0] = v0; buf[q * 4 + 1] = v1;
        buf[q * 4 + 2] = v2; buf[q * 4 + 3] = v3;
        lmax = fmaxf(lmax, fmaxf(fmaxf(v0, v1), fmaxf(v2, v3)));
    }
    #pragma unroll
    for (int o = 1; o < 64; o <<= 1) lmax = fmaxf(lmax, __shfl_xor(lmax, o));
    if ((tid & 63) == 0) red[tid >> 6] = lmax;
    __syncthreads();
    float bmax = fmaxf(fmaxf(red[0], red[1]), fmaxf(red[2], red[3]));

    float lsum = 0.f;
    for (int c = tid; c < cols; c += 256) {
        float e = expf(buf[c] - bmax);
        buf[c] = e;
        lsum += e;
    }
    #pragma unroll
    for (int o = 1; o < 64; o <<= 1) lsum += __shfl_xor(lsum, o);
    __syncthreads();
    if ((tid & 63) == 0) red[tid >> 6] = lsum;
    __syncthreads();
    float inv = 1.0f / (red[0] + red[1] + red[2] + red[3]);

    for (int q = tid; q < nq; q += 256) {
        ushort4 h;
        h.x = f2h(buf[q * 4 + 0] * inv);
        h.y = f2h(buf[q * 4 + 1] * inv);
        h.z = f2h(buf[q * 4 + 2] * inv);
        h.w = f2h(buf[q * 4 + 3] * inv);
        ((ushort4*)p)[q] = h;
    }
}

// ---------------- launch ----------------
extern "C" void kernel_launch(void* const* d_in, const int* in_sizes, int n_in,
                              void* d_out, int out_size, void* d_ws, size_t ws_size,
                              hipStream_t stream) {
    (void)in_sizes; (void)n_in; (void)out_size; (void)ws_size;
    const float* x  = (const float*)d_in[0];
    const float* g  = (const float*)d_in[1];
    const float* Wq = (const float*)d_in[2];
    const float* Wg = (const float*)d_in[3];
    float* out = (float*)d_out;

    const size_t GE = (size_t)Mrows * Cdim;      // 7,864,320 elems
    char* ws = (char*)d_ws;
    size_t off = 0;
    auto alloc = [&](size_t bytes) { char* p = ws + off; off += (bytes + 255) & ~(size_t)255; return p; };

    float* meang = (float*)alloc(Bsz * Cdim * 4);
    float* part  = (float*)alloc(Bsz * 40 * Cdim * 4);
    float* invn  = (float*)alloc(Mrows * 4);
    unsigned short* gh   = (unsigned short*)alloc(GE * 2);            // g f16
    unsigned short* gTh  = (unsigned short*)alloc(GE * 2);            // [NBLK][512][192]
    unsigned short* qh   = (unsigned short*)alloc(GE * 2);            // q f16; reused as g2T
    unsigned short* wqh  = (unsigned short*)alloc((size_t)Cdim * Cdim * 2);
    unsigned short* wgh  = (unsigned short*)alloc((size_t)Cdim * Cdim * 2);
    unsigned short* rqh  = (unsigned short*)alloc(GE * 2);
    unsigned short* rgh  = (unsigned short*)alloc(GE * 2);
    unsigned short* g2h  = (unsigned short*)alloc(GE * 2);
    unsigned short* sbh  = (unsigned short*)alloc((size_t)NBLK * BLK * BLK * 2);
    unsigned short* s2h  = (unsigned short*)alloc((size_t)Bsz * Ntok * Ntok * 2);  // 59 MB
    unsigned short* g2Th = qh;                                        // [Bsz][512][1920]

    // 1. token mean; per-row inv norms (f32 sources)
    mean_partial<<<dim3(Bsz, 40), 512, 0, stream>>>(g, part);
    mean_final<<<Bsz, 512, 0, stream>>>(part, meang);
    invnorm_k<<<Mrows / 4, 256, 0, stream>>>(g, invn);

    // 2. f16 conversions
    cvt_k<<<(int)(GE / 4 + 255) / 256, 256, 0, stream>>>(g, nullptr, gh, (int)(GE / 4));
    cvt_k<<<(int)(GE / 4 + 255) / 256, 256, 0, stream>>>(x, meang, qh, (int)(GE / 4));
    cvt_k<<<(Cdim * Cdim / 4) / 256, 256, 0, stream>>>(Wq, nullptr, wqh, Cdim * Cdim / 4);
    cvt_k<<<(Cdim * Cdim / 4) / 256, 256, 0, stream>>>(Wg, nullptr, wgh, Cdim * Cdim / 4);

    // 2b. gT: per 192-block transpose  [NBLK][512][192]
    transpose1<<<dim3(Cdim / 64, BLK / 64, NBLK), 256, 0, stream>>>(
        gh, gTh, BLK, Cdim, (long)BLK * Cdim, (long)Cdim * BLK);

    // 3. rel_q = q @ Wq^T -> f16  [15360,512]  (<2,4> BK64, 960 blocks)
    mfma_gemm<2, 4, 64><<<dim3(Cdim / 128, Mrows / 64), 256, 0, stream>>>(
        qh, wqh, nullptr, rqh, Cdim, Cdim, Cdim, 0, 0, 0, 1.0f, nullptr, nullptr, 0);

    // 4. block scores = (g·g^T)*invn_i*invn_j*SCALE -> f16  [80][192][192]  (720 blocks)
    mfma_gemm<2, 2, 32><<<dim3(3, 3, NBLK), 256, 0, stream>>>(
        gh, gh, nullptr, sbh, BLK, Cdim, Cdim,
        (long)BLK * Cdim, (long)BLK * Cdim, (long)BLK * BLK,
        SCALE, invn, invn, BLK);

    // 5. block softmax in place
    softmax_h<<<NBLK * BLK, 256, 0, stream>>>(sbh, BLK);

    // 6. g2 = attn · (gT)^T -> f16  [80][192][512]  (<2,4> BK64, 960 blocks, K=192)
    mfma_gemm<2, 4, 64><<<dim3(Cdim / 128, BLK / 64, NBLK), 256, 0, stream>>>(
        sbh, gTh, nullptr, g2h, Cdim, BLK, BLK,
        (long)BLK * BLK, (long)Cdim * BLK, (long)BLK * Cdim,
        1.0f, nullptr, nullptr, 0);

    // 6b. g2T: per-batch transpose  [Bsz][512][1920]  (into dead q buffer)
    transpose1<<<dim3(Cdim / 64, Ntok / 64, Bsz), 256, 0, stream>>>(
        g2h, g2Th, Ntok, Cdim, (long)Ntok * Cdim, (long)Cdim * Ntok);

    // 7. rel_g = g2 @ Wg^T -> f16  [15360,512]  (<2,4> BK64, 960 blocks)
    mfma_gemm<2, 4, 64><<<dim3(Cdim / 128, Mrows / 64), 256, 0, stream>>>(
        g2h, wgh, nullptr, rgh, Cdim, Cdim, Cdim, 0, 0, 0, 1.0f, nullptr, nullptr, 0);

    // 8. global scores = rel_q @ rel_g^T * SCALE -> f16  [8][1920][1920]
    gemm256<<<dim3(8, 8, Bsz), 512, 0, stream>>>(
        rqh, rgh, s2h, Ntok, Ntok, Cdim, Cdim,
        (long)Ntok * Cdim, (long)Ntok * Cdim, (long)Ntok * Ntok, SCALE);

    // 9. global softmax in place  (15360 rows of 1920)
    softmax_h<<<Bsz * Ntok, 256, 0, stream>>>(s2h, Ntok);

    // 10. out = attn2 · (g2T)^T -> f32  [8][1920][512]  (<4,4> BK64, 480 blocks, K=1920)
    mfma_gemm<4, 4, 64><<<dim3(Cdim / 128, Ntok / 128, Bsz), 256, 0, stream>>>(
        s2h, g2Th, out, nullptr, Cdim, Ntok, Ntok,
        (long)Ntok * Ntok, (long)Cdim * Ntok, (long)Ntok * Cdim,
        1.0f, nullptr, nullptr, 0);
}